// Round 8
// baseline (536.345 us; speedup 1.0000x reference)
//
#include <hip/hip_runtime.h>
#include <hip/hip_bf16.h>
#include <stdint.h>

typedef __hip_bfloat16 bf16;
typedef short bf16x8 __attribute__((ext_vector_type(8)));
typedef float f32x4 __attribute__((ext_vector_type(4)));

#define NN 100000
#define NE 1600000
#define DD 64
#define NL 3
#define NG 128
#define BN_EPS 1e-5f
#define SCAN_BLK 98  // ceil(NN / 1024)
#define TILE_ROWS 64
#define LSW 72       // padded bf16 row stride (144 B: 16B-aligned frags, <=2-way banks)
#define NT ((NN + TILE_ROWS - 1) / TILE_ROWS)  // 1563
#define GB_NODES 48
#define GB_BLOCKS ((NN + GB_NODES - 1) / GB_NODES)  // 2084
#define ECAP 1664    // staged padded edges per block (mean ~936)
#define CSW_CAP (NE + 7 * NN)  // padded CSR worst case (int slots)
#define WFL 8192     // shorts per layer of precomputed W fragments (2hl x 2ks x 4nt x 64lane x 8)

// binned fill parameters
#define NBUK 391     // dst buckets of 256 nodes (d >> 8); 391*256 >= NN
#define BUK_CAP 4608 // mean 4096 + 8 sigma
#define OVF_CAP 8192
#define EPB 4096     // edges per bin block (16 per thread)
#define NBB ((NE + EPB - 1) / EPB)  // 391

__device__ __forceinline__ int ld_src(const int* ei, int e, int is32) {
    return is32 ? ei[e] : ei[2 * e];
}
__device__ __forceinline__ int ld_dst(const int* ei, int e, int is32) {
    return is32 ? ei[NE + e] : ei[2 * NE + 2 * e];
}
__device__ __forceinline__ int ld_batch(const int* b, int n, int is32) {
    return is32 ? b[n] : b[2 * n];
}
__device__ __forceinline__ float bf2f(unsigned short u) {
    return __uint_as_float(((unsigned int)u) << 16);
}
__device__ __forceinline__ unsigned short f2bf(float x) {
    bf16 b = __float2bfloat16(x);  // RNE
    return *reinterpret_cast<unsigned short*>(&b);
}
__device__ __forceinline__ void split_bf16(float x, unsigned short& hi, unsigned short& lo) {
    hi = f2bf(x);
    lo = f2bf(x - bf2f(hi));
}
__device__ __forceinline__ int pad8(int d) { return (d + 7) & ~7; }

// ---------------- bin pass 1: edges -> 391 dst-range buckets (self-detect int width) ----
__global__ __launch_bounds__(256) void bin_kernel(const int* __restrict__ ei,
                                                  int* __restrict__ deg_cnt,
                                                  int* __restrict__ bukcnt,
                                                  int* __restrict__ staging,
                                                  int* __restrict__ ovf_cnt,
                                                  int2* __restrict__ ovf) {
    __shared__ int hist[NBUK];
    __shared__ int base[NBUK];
    __shared__ int s_e;
    if (threadIdx.x == 0) s_e = 0;
    for (int i = threadIdx.x; i < NBUK; i += 256) hist[i] = 0;
    __syncthreads();
    // int32-vs-int64 detect: odd int-slots are src values (int32) or high words (int64)
    if (ei[2 * threadIdx.x + 1] != 0) atomicOr(&s_e, 1);
    __syncthreads();
    int is32 = s_e;

    int e0 = blockIdx.x * EPB;
    int myb[16], mypack[16], myidx[16];
#pragma unroll
    for (int k = 0; k < 16; ++k) {
        int e = e0 + k * 256 + threadIdx.x;
        myb[k] = -1;
        if (e < NE) {
            int s = ld_src(ei, e, is32), d = ld_dst(ei, e, is32);
            int b = d >> 8;
            myb[k] = b;
            mypack[k] = (s << 8) | (d & 255);
            myidx[k] = atomicAdd(&hist[b], 1);
        }
    }
    __syncthreads();
    for (int i = threadIdx.x; i < NBUK; i += 256)
        if (hist[i]) base[i] = atomicAdd(&bukcnt[i], hist[i]);
    __syncthreads();
#pragma unroll
    for (int k = 0; k < 16; ++k) {
        if (myb[k] >= 0) {
            int slot = base[myb[k]] + myidx[k];
            if (slot < BUK_CAP) {
                staging[myb[k] * BUK_CAP + slot] = mypack[k];
            } else {  // essentially-never overflow path (correctness guarantee)
                int d = (myb[k] << 8) | (mypack[k] & 255);
                atomicAdd(&deg_cnt[d], 1);  // overflow degree contribution
                int o = atomicAdd(ovf_cnt, 1);
                if (o < OVF_CAP) ovf[o] = make_int2(mypack[k] >> 8, d);
            }
        }
    }
}

// ---------------- scan phase 1: deg from staging hist (+ ovf), padded totals, dinv ------
__global__ __launch_bounds__(256) void scan_part_kernel(int* __restrict__ deg_cnt,
                                                        const int* __restrict__ bukcnt,
                                                        const int* __restrict__ staging,
                                                        int* __restrict__ blocksum,
                                                        float* __restrict__ dinv) {
    __shared__ int hist[1024];
    __shared__ int s[256];
    for (int i = threadIdx.x; i < 1024; i += 256) hist[i] = 0;
    __syncthreads();
    int b4 = blockIdx.x * 4;
#pragma unroll
    for (int j = 0; j < 4; ++j) {
        int bk = b4 + j;
        if (bk < NBUK) {
            int n = min(bukcnt[bk], BUK_CAP);
            const int* st = staging + bk * BUK_CAP;
            for (int i = threadIdx.x; i < n; i += 256)
                atomicAdd(&hist[(j << 8) | (st[i] & 255)], 1);
        }
    }
    __syncthreads();
    int base = blockIdx.x * 1024 + threadIdx.x * 4;
    int t = 0;
    if (base < NN) {  // NN % 4 == 0 -> whole int4 in-bounds
        int4 ov = *(const int4*)(deg_cnt + base);              // overflow counts (~0)
        int4 hv = *(const int4*)(hist + threadIdx.x * 4);      // local hist
        int4 v = make_int4(ov.x + hv.x, ov.y + hv.y, ov.z + hv.z, ov.w + hv.w);
        *(int4*)(deg_cnt + base) = v;                          // true degree (coalesced)
        t = pad8(v.x) + pad8(v.y) + pad8(v.z) + pad8(v.w);
        float4 dv = make_float4(rsqrtf((float)v.x + 1.f), rsqrtf((float)v.y + 1.f),
                                rsqrtf((float)v.z + 1.f), rsqrtf((float)v.w + 1.f));
        *(float4*)(dinv + base) = dv;  // +1 self-loop
    }
    s[threadIdx.x] = t;
    __syncthreads();
    for (int off = 128; off > 0; off >>= 1) {
        if (threadIdx.x < off) s[threadIdx.x] += s[threadIdx.x + off];
        __syncthreads();
    }
    if (threadIdx.x == 0) blocksum[blockIdx.x] = s[0];
}

// ---------------- scan phase 2 (+ piggybacked W-fragment prep in blocks >= SCAN_BLK) ----
__global__ __launch_bounds__(256) void scan_write_kernel(int* __restrict__ deg_cnt,
                                                         const int* __restrict__ blocksum,
                                                         int* __restrict__ rowptr,
                                                         const float* __restrict__ Ws,
                                                         unsigned short* __restrict__ wfrag) {
    if (blockIdx.x >= SCAN_BLK) {  // W-prep: split W into hi/lo fragments, once per layer
        int l = blockIdx.x - SCAN_BLK;  // 0..NL-1
        const float* W = Ws + (size_t)l * DD * DD;
        unsigned short* wf = wfrag + (size_t)l * WFL;
        for (int slot = threadIdx.x; slot < 512; slot += 256) {
            int lane = slot & 63, nt = (slot >> 6) & 3, ks = slot >> 8;
            int lr = lane & 15, lg = lane >> 4;
#pragma unroll
            for (int e = 0; e < 8; ++e) {
                float wval = W[(ks * 32 + lg * 8 + e) * DD + nt * 16 + lr];
                unsigned short hi, lo;
                split_bf16(wval, hi, lo);
                wf[((0 * 2 + ks) * 4 + nt) * 512 + lane * 8 + e] = hi;
                wf[((1 * 2 + ks) * 4 + nt) * 512 + lane * 8 + e] = lo;
            }
        }
        return;
    }
    __shared__ int sb[128];
    __shared__ int s[256];
    if (threadIdx.x < 128)
        sb[threadIdx.x] = (threadIdx.x < SCAN_BLK) ? blocksum[threadIdx.x] : 0;
    __syncthreads();
    for (int off = 1; off < 128; off <<= 1) {
        int a = 0;
        if (threadIdx.x < 128 && threadIdx.x >= off) a = sb[threadIdx.x - off];
        __syncthreads();
        if (threadIdx.x < 128) sb[threadIdx.x] += a;
        __syncthreads();
    }
    int blockpre = (blockIdx.x == 0) ? 0 : sb[blockIdx.x - 1];
    if (blockIdx.x == SCAN_BLK - 1 && threadIdx.x == 0)
        rowptr[NN] = sb[SCAN_BLK - 1];  // padded total

    int base = blockIdx.x * 1024 + threadIdx.x * 4;
    int4 v = make_int4(0, 0, 0, 0);
    if (base < NN) v = *(const int4*)(deg_cnt + base);
    int p0 = pad8(v.x), p1 = pad8(v.y), p2 = pad8(v.z), p3 = pad8(v.w);
    int t = p0 + p1 + p2 + p3;
    s[threadIdx.x] = t;
    for (int off = 1; off < 256; off <<= 1) {
        __syncthreads();
        int a = (threadIdx.x >= off) ? s[threadIdx.x - off] : 0;
        __syncthreads();
        s[threadIdx.x] += a;
    }
    __syncthreads();
    int pre = blockpre + s[threadIdx.x] - t;  // exclusive padded prefix
    if (base < NN) {
        rowptr[base] = pre;
        rowptr[base + 1] = pre + p0;
        rowptr[base + 2] = pre + p0 + p1;
        rowptr[base + 3] = pre + p0 + p1 + p2;
        *(int4*)(deg_cnt + base) = make_int4(0, 0, 0, 0);  // becomes scatter cursor
    }
}

// ---------------- scatter body (bucket -> CSR; window L2-resident) ----------------
__device__ __forceinline__ void scatter_body(int b, const int* __restrict__ bukcnt,
                                             const int* __restrict__ staging,
                                             const int* __restrict__ ovf_cnt,
                                             const int2* __restrict__ ovf,
                                             const int* __restrict__ rowptr,
                                             int* __restrict__ cursor,
                                             int* __restrict__ csw) {
    if (b == NBUK) {
        int n = min(*ovf_cnt, OVF_CAP);
        for (int i = threadIdx.x; i < n; i += 256) {
            int2 e = ovf[i];
            int pos = rowptr[e.y] + atomicAdd(&cursor[e.y], 1);
            csw[pos] = (e.x + 1) << 7;
        }
        return;
    }
    int n = min(bukcnt[b], BUK_CAP);
    int nb = b << 8;
    const int* st = staging + b * BUK_CAP;
    for (int i = threadIdx.x; i < n; i += 256) {
        int v = st[i];
        int d = nb + (v & 255);
        int pos = rowptr[d] + atomicAdd(&cursor[d], 1);
        csw[pos] = ((v >> 8) + 1) << 7;  // byte offset from zero-row base
    }
}

// ---------------- gemm body: MFMA bf16x3-split; t' = act(BN(h)) @ W * dinv[row] --------
struct GemmSmem {
    unsigned short ls_hi[TILE_ROWS * LSW];  // 9216 B (also epilogue repack)
    unsigned short ls_lo[TILE_ROWS * LSW];  // 9216 B
    float ssc[DD], ssh[DD], sdinv[TILE_ROWS];
};

__device__ __forceinline__ void gemm_body(GemmSmem& sm,
                                          const float* __restrict__ h,
                                          const unsigned short* __restrict__ wf,
                                          const float* __restrict__ dinv,
                                          const float* __restrict__ accum_prev,
                                          const float* __restrict__ gamma,
                                          const float* __restrict__ beta,
                                          int use_bn, float alpha,
                                          bf16* __restrict__ t,
                                          float* __restrict__ accum_l,
                                          int do_zero, int tile0, int tstride) {
    if (do_zero && threadIdx.x < 128) accum_l[threadIdx.x] = 0.f;
    int tid = threadIdx.x;
    if (tid < 64) {
        if (use_bn) {
            float S = accum_prev[tid], Q = accum_prev[64 + tid];
            float mean = S / (float)NN;
            float var = fmaxf(Q / (float)NN - mean * mean, 0.f);
            float sc = gamma[tid] * rsqrtf(var + BN_EPS);
            sm.ssc[tid] = sc;
            sm.ssh[tid] = beta[tid] - mean * sc;
        } else {
            sm.ssc[tid] = 1.f;
            sm.ssh[tid] = 0.f;
        }
    }

    int lane = tid & 63;
    int wv = tid >> 6;   // wave 0..3 -> rows wv*16..wv*16+15
    int lr = lane & 15;  // row-in-tile / col-in-tile
    int lg = lane >> 4;  // k-group 0..3

    // B fragments: precomputed hi/lo splits, coalesced 16B loads
    bf16x8 bhi[2][4], blo[2][4];
#pragma unroll
    for (int ks = 0; ks < 2; ++ks)
#pragma unroll
        for (int nt = 0; nt < 4; ++nt) {
            bhi[ks][nt] = *(const bf16x8*)(wf + ((0 * 2 + ks) * 4 + nt) * 512 + lane * 8);
            blo[ks][nt] = *(const bf16x8*)(wf + ((1 * 2 + ks) * 4 + nt) * 512 + lane * 8);
        }
    __syncthreads();  // ssc/ssh ready

    for (int tile = tile0; tile < NT; tile += tstride) {
        int row0 = tile * TILE_ROWS;
        int nrows = min(TILE_ROWS, NN - row0);
        if (tid < 64) sm.sdinv[tid] = (row0 + tid < NN) ? dinv[row0 + tid] : 0.f;
        // stage activated tile as hi/lo bf16
#pragma unroll
        for (int it = 0; it < 4; ++it) {
            int flat = (tid + it * 256) * 4;  // 0..16380
            int gflat = row0 * DD + flat;
            if (gflat < NN * DD) {
                float4 hv = *(const float4*)(h + gflat);
                int c0 = flat & 63;
                float4 s4 = *(const float4*)(sm.ssc + c0);
                float4 b4 = *(const float4*)(sm.ssh + c0);
                float x0 = hv.x * s4.x + b4.x;
                float x1 = hv.y * s4.y + b4.y;
                float x2 = hv.z * s4.z + b4.z;
                float x3 = hv.w * s4.w + b4.w;
                x0 = fmaxf(x0, x0 * alpha);
                x1 = fmaxf(x1, x1 * alpha);
                x2 = fmaxf(x2, x2 * alpha);
                x3 = fmaxf(x3, x3 * alpha);
                unsigned short h0, l0, h1, l1, h2, l2, h3, l3;
                split_bf16(x0, h0, l0);
                split_bf16(x1, h1, l1);
                split_bf16(x2, h2, l2);
                split_bf16(x3, h3, l3);
                int row = flat >> 6;
                *(ushort4*)(sm.ls_hi + row * LSW + c0) = make_ushort4(h0, h1, h2, h3);
                *(ushort4*)(sm.ls_lo + row * LSW + c0) = make_ushort4(l0, l1, l2, l3);
            }
        }
        __syncthreads();

        f32x4 acc[4];
#pragma unroll
        for (int nt = 0; nt < 4; ++nt) acc[nt] = (f32x4){0.f, 0.f, 0.f, 0.f};

#pragma unroll
        for (int ks = 0; ks < 2; ++ks) {
            int aoff = (wv * 16 + lr) * LSW + ks * 32 + lg * 8;  // 16B-aligned
            bf16x8 a_hi = *(const bf16x8*)(sm.ls_hi + aoff);
            bf16x8 a_lo = *(const bf16x8*)(sm.ls_lo + aoff);
#pragma unroll
            for (int nt = 0; nt < 4; ++nt) {
                acc[nt] = __builtin_amdgcn_mfma_f32_16x16x32_bf16(a_hi, bhi[ks][nt],
                                                                  acc[nt], 0, 0, 0);
                acc[nt] = __builtin_amdgcn_mfma_f32_16x16x32_bf16(a_hi, blo[ks][nt],
                                                                  acc[nt], 0, 0, 0);
                acc[nt] = __builtin_amdgcn_mfma_f32_16x16x32_bf16(a_lo, bhi[ks][nt],
                                                                  acc[nt], 0, 0, 0);
            }
        }
        __syncthreads();  // all A-frag reads done; ls_hi reusable for repack

        // repack D*dinv -> bf16 tile in LDS, then coalesced store
#pragma unroll
        for (int nt = 0; nt < 4; ++nt)
#pragma unroll
            for (int rg = 0; rg < 4; ++rg) {
                int orow = wv * 16 + lg * 4 + rg;
                sm.ls_hi[orow * LSW + nt * 16 + lr] = f2bf(acc[nt][rg] * sm.sdinv[orow]);
            }
        __syncthreads();
#pragma unroll
        for (int it = 0; it < 2; ++it) {
            int flat8 = (tid + it * 256) * 8;  // 0..4088
            int row = flat8 >> 6, c = flat8 & 63;
            if (row < nrows) {
                uint4 v = *(const uint4*)(sm.ls_hi + row * LSW + c);
                *(uint4*)((unsigned short*)t + (size_t)(row0 + row) * DD + c) = v;
            }
        }
        __syncthreads();  // before next tile overwrites ls
    }
}

// ---------------- fused: scatter (blocks 0..NBUK) || gemm layer 0 (rest) ----------------
__global__ __launch_bounds__(256) void scatter_gemm_kernel(
    const int* __restrict__ bukcnt, const int* __restrict__ staging,
    const int* __restrict__ ovf_cnt, const int2* __restrict__ ovf,
    const int* __restrict__ rowptr, int* __restrict__ cursor, int* __restrict__ csw,
    const float* __restrict__ x, const unsigned short* __restrict__ wfrag,
    const float* __restrict__ dinv, bf16* __restrict__ t, float* __restrict__ accum_l) {
    __shared__ GemmSmem sm;
    int b = blockIdx.x;
    if (b <= NBUK) {
        scatter_body(b, bukcnt, staging, ovf_cnt, ovf, rowptr, cursor, csw);
        return;
    }
    int g = b - (NBUK + 1);
    gemm_body(sm, x, wfrag, dinv, nullptr, nullptr, nullptr, 0, 1.0f, t, accum_l,
              g == 0, g, gridDim.x - (NBUK + 1));
}

__global__ __launch_bounds__(256) void gemm_kernel(const float* __restrict__ h,
                                                   const unsigned short* __restrict__ wfrag,
                                                   const float* __restrict__ dinv,
                                                   const float* __restrict__ accum_prev,
                                                   const float* __restrict__ gamma,
                                                   const float* __restrict__ beta,
                                                   bf16* __restrict__ t,
                                                   float* __restrict__ accum_l) {
    __shared__ GemmSmem sm;
    gemm_body(sm, h, wfrag, dinv, accum_prev, gamma, beta, 1, 0.0f, t, accum_l,
              blockIdx.x == 0, blockIdx.x, gridDim.x);
}

// ---------------- gather: 4B edges, weightless adds, 4-node quad per wave ----------------
__device__ __forceinline__ void batch8(const int* __restrict__ ep, int j,
                                       const char* __restrict__ tbase, int f2,
                                       float& acc) {
    int4 a0 = *(const int4*)(ep + j);
    int4 a1 = *(const int4*)(ep + j + 4);
    unsigned short r[8];
    r[0] = *(const unsigned short*)(tbase + (unsigned)(a0.x + f2));
    r[1] = *(const unsigned short*)(tbase + (unsigned)(a0.y + f2));
    r[2] = *(const unsigned short*)(tbase + (unsigned)(a0.z + f2));
    r[3] = *(const unsigned short*)(tbase + (unsigned)(a0.w + f2));
    r[4] = *(const unsigned short*)(tbase + (unsigned)(a1.x + f2));
    r[5] = *(const unsigned short*)(tbase + (unsigned)(a1.y + f2));
    r[6] = *(const unsigned short*)(tbase + (unsigned)(a1.z + f2));
    r[7] = *(const unsigned short*)(tbase + (unsigned)(a1.w + f2));
    float s01 = bf2f(r[0]) + bf2f(r[1]), s23 = bf2f(r[2]) + bf2f(r[3]);
    float s45 = bf2f(r[4]) + bf2f(r[5]), s67 = bf2f(r[6]) + bf2f(r[7]);
    acc += (s01 + s23) + (s45 + s67);
}

__device__ __forceinline__ void batch8x2(const int* __restrict__ ep, int jA, int jB,
                                         const char* __restrict__ tbase, int f2,
                                         float& accA, float& accB) {
    int4 aA0 = *(const int4*)(ep + jA), aA1 = *(const int4*)(ep + jA + 4);
    int4 aB0 = *(const int4*)(ep + jB), aB1 = *(const int4*)(ep + jB + 4);
    unsigned short rA[8], rB[8];
    rA[0] = *(const unsigned short*)(tbase + (unsigned)(aA0.x + f2));
    rA[1] = *(const unsigned short*)(tbase + (unsigned)(aA0.y + f2));
    rA[2] = *(const unsigned short*)(tbase + (unsigned)(aA0.z + f2));
    rA[3] = *(const unsigned short*)(tbase + (unsigned)(aA0.w + f2));
    rA[4] = *(const unsigned short*)(tbase + (unsigned)(aA1.x + f2));
    rA[5] = *(const unsigned short*)(tbase + (unsigned)(aA1.y + f2));
    rA[6] = *(const unsigned short*)(tbase + (unsigned)(aA1.z + f2));
    rA[7] = *(const unsigned short*)(tbase + (unsigned)(aA1.w + f2));
    rB[0] = *(const unsigned short*)(tbase + (unsigned)(aB0.x + f2));
    rB[1] = *(const unsigned short*)(tbase + (unsigned)(aB0.y + f2));
    rB[2] = *(const unsigned short*)(tbase + (unsigned)(aB0.z + f2));
    rB[3] = *(const unsigned short*)(tbase + (unsigned)(aB0.w + f2));
    rB[4] = *(const unsigned short*)(tbase + (unsigned)(aB1.x + f2));
    rB[5] = *(const unsigned short*)(tbase + (unsigned)(aB1.y + f2));
    rB[6] = *(const unsigned short*)(tbase + (unsigned)(aB1.z + f2));
    rB[7] = *(const unsigned short*)(tbase + (unsigned)(aB1.w + f2));
    float sA01 = bf2f(rA[0]) + bf2f(rA[1]), sA23 = bf2f(rA[2]) + bf2f(rA[3]);
    float sA45 = bf2f(rA[4]) + bf2f(rA[5]), sA67 = bf2f(rA[6]) + bf2f(rA[7]);
    accA += (sA01 + sA23) + (sA45 + sA67);
    float sB01 = bf2f(rB[0]) + bf2f(rB[1]), sB23 = bf2f(rB[2]) + bf2f(rB[3]);
    float sB45 = bf2f(rB[4]) + bf2f(rB[5]), sB67 = bf2f(rB[6]) + bf2f(rB[7]);
    accB += (sB01 + sB23) + (sB45 + sB67);
}

__device__ __forceinline__ void batch8x4(const int* __restrict__ ep, int jA, int jB,
                                         int jC, int jD,
                                         const char* __restrict__ tbase, int f2,
                                         float& accA, float& accB, float& accC,
                                         float& accD) {
    int4 aA0 = *(const int4*)(ep + jA), aA1 = *(const int4*)(ep + jA + 4);
    int4 aB0 = *(const int4*)(ep + jB), aB1 = *(const int4*)(ep + jB + 4);
    int4 aC0 = *(const int4*)(ep + jC), aC1 = *(const int4*)(ep + jC + 4);
    int4 aD0 = *(const int4*)(ep + jD), aD1 = *(const int4*)(ep + jD + 4);
    unsigned short rA[8], rB[8], rC[8], rD[8];
    rA[0] = *(const unsigned short*)(tbase + (unsigned)(aA0.x + f2));
    rA[1] = *(const unsigned short*)(tbase + (unsigned)(aA0.y + f2));
    rA[2] = *(const unsigned short*)(tbase + (unsigned)(aA0.z + f2));
    rA[3] = *(const unsigned short*)(tbase + (unsigned)(aA0.w + f2));
    rA[4] = *(const unsigned short*)(tbase + (unsigned)(aA1.x + f2));
    rA[5] = *(const unsigned short*)(tbase + (unsigned)(aA1.y + f2));
    rA[6] = *(const unsigned short*)(tbase + (unsigned)(aA1.z + f2));
    rA[7] = *(const unsigned short*)(tbase + (unsigned)(aA1.w + f2));
    rB[0] = *(const unsigned short*)(tbase + (unsigned)(aB0.x + f2));
    rB[1] = *(const unsigned short*)(tbase + (unsigned)(aB0.y + f2));
    rB[2] = *(const unsigned short*)(tbase + (unsigned)(aB0.z + f2));
    rB[3] = *(const unsigned short*)(tbase + (unsigned)(aB0.w + f2));
    rB[4] = *(const unsigned short*)(tbase + (unsigned)(aB1.x + f2));
    rB[5] = *(const unsigned short*)(tbase + (unsigned)(aB1.y + f2));
    rB[6] = *(const unsigned short*)(tbase + (unsigned)(aB1.z + f2));
    rB[7] = *(const unsigned short*)(tbase + (unsigned)(aB1.w + f2));
    rC[0] = *(const unsigned short*)(tbase + (unsigned)(aC0.x + f2));
    rC[1] = *(const unsigned short*)(tbase + (unsigned)(aC0.y + f2));
    rC[2] = *(const unsigned short*)(tbase + (unsigned)(aC0.z + f2));
    rC[3] = *(const unsigned short*)(tbase + (unsigned)(aC0.w + f2));
    rC[4] = *(const unsigned short*)(tbase + (unsigned)(aC1.x + f2));
    rC[5] = *(const unsigned short*)(tbase + (unsigned)(aC1.y + f2));
    rC[6] = *(const unsigned short*)(tbase + (unsigned)(aC1.z + f2));
    rC[7] = *(const unsigned short*)(tbase + (unsigned)(aC1.w + f2));
    rD[0] = *(const unsigned short*)(tbase + (unsigned)(aD0.x + f2));
    rD[1] = *(const unsigned short*)(tbase + (unsigned)(aD0.y + f2));
    rD[2] = *(const unsigned short*)(tbase + (unsigned)(aD0.z + f2));
    rD[3] = *(const unsigned short*)(tbase + (unsigned)(aD0.w + f2));
    rD[4] = *(const unsigned short*)(tbase + (unsigned)(aD1.x + f2));
    rD[5] = *(const unsigned short*)(tbase + (unsigned)(aD1.y + f2));
    rD[6] = *(const unsigned short*)(tbase + (unsigned)(aD1.z + f2));
    rD[7] = *(const unsigned short*)(tbase + (unsigned)(aD1.w + f2));
    float sA01 = bf2f(rA[0]) + bf2f(rA[1]), sA23 = bf2f(rA[2]) + bf2f(rA[3]);
    float sA45 = bf2f(rA[4]) + bf2f(rA[5]), sA67 = bf2f(rA[6]) + bf2f(rA[7]);
    accA += (sA01 + sA23) + (sA45 + sA67);
    float sB01 = bf2f(rB[0]) + bf2f(rB[1]), sB23 = bf2f(rB[2]) + bf2f(rB[3]);
    float sB45 = bf2f(rB[4]) + bf2f(rB[5]), sB67 = bf2f(rB[6]) + bf2f(rB[7]);
    accB += (sB01 + sB23) + (sB45 + sB67);
    float sC01 = bf2f(rC[0]) + bf2f(rC[1]), sC23 = bf2f(rC[2]) + bf2f(rC[3]);
    float sC45 = bf2f(rC[4]) + bf2f(rC[5]), sC67 = bf2f(rC[6]) + bf2f(rC[7]);
    accC += (sC01 + sC23) + (sC45 + sC67);
    float sD01 = bf2f(rD[0]) + bf2f(rD[1]), sD23 = bf2f(rD[2]) + bf2f(rD[3]);
    float sD45 = bf2f(rD[4]) + bf2f(rD[5]), sD67 = bf2f(rD[6]) + bf2f(rD[7]);
    accD += (sD01 + sD23) + (sD45 + sD67);
}

// drain chain: x4 while all alive, then every x2 pairing, then singles.
// All bounds are wave-uniform (per-node), so branches don't diverge.
__device__ __forceinline__ void run_quad(const int* __restrict__ ep,
                                         const char* __restrict__ tbase, int f2,
                                         int jA, int eA, int jB, int eB,
                                         int jC, int eC, int jD, int eD,
                                         float& accA, float& accB, float& accC,
                                         float& accD) {
    while (jA < eA && jB < eB && jC < eC && jD < eD) {
        batch8x4(ep, jA, jB, jC, jD, tbase, f2, accA, accB, accC, accD);
        jA += 8; jB += 8; jC += 8; jD += 8;
    }
    while (jA < eA && jB < eB) { batch8x2(ep, jA, jB, tbase, f2, accA, accB); jA += 8; jB += 8; }
    while (jC < eC && jD < eD) { batch8x2(ep, jC, jD, tbase, f2, accC, accD); jC += 8; jD += 8; }
    while (jA < eA && jC < eC) { batch8x2(ep, jA, jC, tbase, f2, accA, accC); jA += 8; jC += 8; }
    while (jA < eA && jD < eD) { batch8x2(ep, jA, jD, tbase, f2, accA, accD); jA += 8; jD += 8; }
    while (jB < eB && jC < eC) { batch8x2(ep, jB, jC, tbase, f2, accB, accC); jB += 8; jC += 8; }
    while (jB < eB && jD < eD) { batch8x2(ep, jB, jD, tbase, f2, accB, accD); jB += 8; jD += 8; }
    while (jA < eA) { batch8(ep, jA, tbase, f2, accA); jA += 8; }
    while (jB < eB) { batch8(ep, jB, tbase, f2, accB); jB += 8; }
    while (jC < eC) { batch8(ep, jC, tbase, f2, accC); jC += 8; }
    while (jD < eD) { batch8(ep, jD, tbase, f2, accD); jD += 8; }
}

__global__ __launch_bounds__(256) void gather_kernel(const bf16* __restrict__ t,
                                                     const float* __restrict__ dinv,
                                                     const float* __restrict__ bias,
                                                     const int* __restrict__ rowptr,
                                                     const int* __restrict__ csw,
                                                     float* __restrict__ h,
                                                     float* __restrict__ accum_l) {
    __shared__ __attribute__((aligned(16))) int se[ECAP];  // 6.5 KB staged byte-offsets
    __shared__ int srp[GB_NODES + 1];  // staged rowptr slice
    __shared__ float s_sum[256], s_sq[256];

    int f = threadIdx.x & 63;
    int wv = threadIdx.x >> 6;
    int nb0 = blockIdx.x * GB_NODES;
    int nloc = min(GB_NODES, NN - nb0);  // 48 or 16; always multiple of 4

    for (int i = threadIdx.x; i <= nloc; i += 256) srp[i] = rowptr[nb0 + i];
    __syncthreads();
    int ebase = srp[0];
    int nE = srp[nloc] - ebase;  // multiple of 8
    bool staged = (nE <= ECAP);
    if (staged) {  // vectorized stage: ebase, nE multiples of 8 -> int4 aligned
        for (int i = threadIdx.x * 4; i < nE; i += 1024)
            *(int4*)(se + i) = *(const int4*)(csw + ebase + i);
    }
    __syncthreads();

    const char* tbase = (const char*)t - 128;  // zero-row base (pad slot 0 -> zeros)
    int f2 = f * 2;
    const unsigned short* tf = (const unsigned short*)t + f;
    float bb = bias[f];
    float sum = 0.f, sq = 0.f;

    for (int q = wv; 4 * q < nloc; q += 4) {  // wave handles node quad 4q..4q+3
        int d0 = 4 * q;
        int nA = nb0 + d0, nB = nA + 1, nC = nA + 2, nD = nA + 3;
        // init with self-loop t'[n]; dinv[n] applied at the end
        float accA = bf2f(tf[(size_t)nA * DD]);
        float accB = bf2f(tf[(size_t)nB * DD]);
        float accC = bf2f(tf[(size_t)nC * DD]);
        float accD = bf2f(tf[(size_t)nD * DD]);
        int jA = srp[d0] - ebase, eA = srp[d0 + 1] - ebase;  // multiples of 8
        int jB = eA, eB = srp[d0 + 2] - ebase;
        int jC = eB, eC = srp[d0 + 3] - ebase;
        int jD = eC, eD = srp[d0 + 4] - ebase;

        if (staged)
            run_quad(se, tbase, f2, jA, eA, jB, eB, jC, eC, jD, eD, accA, accB, accC, accD);
        else  // overflow block (vanishingly rare): csw from global
            run_quad(csw + ebase, tbase, f2, jA, eA, jB, eB, jC, eC, jD, eD,
                     accA, accB, accC, accD);

        float diA = dinv[nA], diB = dinv[nB], diC = dinv[nC], diD = dinv[nD];
        accA = accA * diA + bb;
        accB = accB * diB + bb;
        accC = accC * diC + bb;
        accD = accD * diD + bb;
        h[(size_t)nA * DD + f] = accA;
        h[(size_t)nB * DD + f] = accB;
        h[(size_t)nC * DD + f] = accC;
        h[(size_t)nD * DD + f] = accD;
        sum += accA + accB + accC + accD;
        sq += accA * accA + accB * accB + accC * accC + accD * accD;
    }
    s_sum[threadIdx.x] = sum;
    s_sq[threadIdx.x] = sq;
    __syncthreads();
    if (threadIdx.x < 64) {
        sum = s_sum[f] + s_sum[64 + f] + s_sum[128 + f] + s_sum[192 + f];
        sq = s_sq[f] + s_sq[64 + f] + s_sq[128 + f] + s_sq[192 + f];
        atomicAdd(&accum_l[f], sum);
        atomicAdd(&accum_l[64 + f], sq);
    }
}

// ---------------- pool: BN finalize(layer3) + ReLU + mean-pool + fused final ----------------
#define POOL_CHUNK 128
__global__ __launch_bounds__(256) void pool_kernel(const float* __restrict__ hraw,
                                                   const float* __restrict__ accum_l,
                                                   const float* __restrict__ gamma,
                                                   const float* __restrict__ beta,
                                                   const int* __restrict__ batch,
                                                   float* __restrict__ pool,
                                                   float* __restrict__ counts,
                                                   int* __restrict__ done,
                                                   float* __restrict__ out) {
    __shared__ float ssc[64], ssh[64];
    __shared__ float scnt[NG];
    __shared__ int s_b;
    __shared__ int isLast;
    if (threadIdx.x == 0) s_b = 0;
    if (threadIdx.x < 64) {
        float S = accum_l[threadIdx.x], Q = accum_l[64 + threadIdx.x];
        float mean = S / (float)NN;
        float var = fmaxf(Q / (float)NN - mean * mean, 0.f);
        float sc = gamma[threadIdx.x] * rsqrtf(var + BN_EPS);
        ssc[threadIdx.x] = sc;
        ssh[threadIdx.x] = beta[threadIdx.x] - mean * sc;
    }
    __syncthreads();
    // batch width detect: tail odd slots are values ~127 (int32) or high words (int64)
    if (batch[NN - 1024 + 2 * threadIdx.x + 1] != 0) atomicOr(&s_b, 1);
    __syncthreads();
    int is32 = s_b;
    int f = threadIdx.x & 63, rg = threadIdx.x >> 6;
    float sc = ssc[f], sh = ssh[f];
    int base = blockIdx.x * POOL_CHUNK;
    float acc = 0.f, cnt = 0.f;
    int cur = -1;
    for (int i = rg; i < POOL_CHUNK; i += 4) {
        int n = base + i;
        if (n >= NN) break;
        int g = ld_batch(batch, n, is32);
        if (g != cur) {
            if (cur >= 0) {
                atomicAdd(&pool[cur * DD + f], acc);
                if (f == 0) atomicAdd(&counts[cur], cnt);
            }
            acc = 0.f;
            cnt = 0.f;
            cur = g;
        }
        acc += fmaxf(hraw[(size_t)n * DD + f] * sc + sh, 0.f);
        cnt += 1.f;
    }
    if (cur >= 0) {
        atomicAdd(&pool[cur * DD + f], acc);
        if (f == 0) atomicAdd(&counts[cur], cnt);
    }
    // fused final: last block to finish divides and writes out.
    __threadfence();
    if (threadIdx.x == 0) isLast = (atomicAdd(done, 1) == (int)gridDim.x - 1);
    __syncthreads();
    if (isLast) {
        // read via atomicAdd(+0) so reads resolve at the device coherence point
        for (int i = threadIdx.x; i < NG; i += 256) scnt[i] = atomicAdd(&counts[i], 0.f);
        __syncthreads();
        for (int i = threadIdx.x; i < NG * DD; i += 256) {
            float v = atomicAdd(&pool[i], 0.f);
            out[i] = v / fmaxf(scnt[i >> 6], 1.0f);
        }
    }
}

extern "C" void kernel_launch(void* const* d_in, const int* in_sizes, int n_in,
                              void* d_out, int out_size, void* d_ws, size_t ws_size,
                              hipStream_t stream) {
    const float* x = (const float*)d_in[0];       // [NN, DD] f32
    const int* edge_index = (const int*)d_in[1];  // [2, NE] int (width detected)
    const int* batch = (const int*)d_in[2];       // [NN] int (width detected)
    const float* Ws = (const float*)d_in[3];      // [3,64,64]
    const float* bs = (const float*)d_in[4];      // [3,64]
    const float* gammas = (const float*)d_in[5];  // [3,64]
    const float* betas = (const float*)d_in[6];   // [3,64]
    float* out = (float*)d_out;                   // [NG, DD]

    // workspace layout
    float* h = (float*)d_ws;                    // 25.6 MB (bin staging before gather 0)
    bf16* zrow = (bf16*)(h + (size_t)NN * DD);  // 128 B zero row (pad-slot target)
    bf16* t = zrow + DD;                        // 12.8 MB (t' = scaled transform)
    int* csw = (int*)(t + (size_t)NN * DD);     // CSW_CAP int (9.2 MB, padded CSR)
    float* dinv = (float*)(csw + CSW_CAP);      // 100,000 f
    int* deg_cnt = (int*)(dinv + NN);           // 100,000 i (deg, then scatter cursor)
    float* pool = (float*)(deg_cnt + NN);       // 8192 f
    float* counts = pool + NG * DD;             // 128 f
    int* bukcnt = (int*)(counts + NG);          // NBUK i
    int* ovf_cnt = bukcnt + NBUK;               // 1 i
    int* done = ovf_cnt + 1;                    // 1 i (pool completion counter)
    int* rowptr = done + 1;                     // 100,001 i (padded CSR offsets)
    float* accum = (float*)(rowptr + NN + 1);   // NL*128 f (BN sum/sumsq per layer)
    int* blocksum = (int*)(accum + NL * 128);   // 128 i
    unsigned short* wfrag =                     // NL*WFL shorts (48 KB), 16B-aligned
        (unsigned short*)(((uintptr_t)(blocksum + 128) + 15) & ~(uintptr_t)15);
    int2* ovf = (int2*)(wfrag + (size_t)NL * WFL);  // OVF_CAP int2 (16B-aligned)
    int* staging = (int*)h;                     // NBUK*BUK_CAP ints = 7.2 MB

    // one memset covers deg_cnt + pool + counts + bukcnt + ovf_cnt + done (contiguous)
    hipMemsetAsync(deg_cnt, 0, (NN + NG * DD + NG + NBUK + 2) * sizeof(int), stream);
    hipMemsetAsync(csw, 0, (size_t)CSW_CAP * sizeof(int), stream);  // pads -> zero-row
    hipMemsetAsync(zrow, 0, DD * sizeof(bf16), stream);

    bin_kernel<<<NBB, 256, 0, stream>>>(edge_index, deg_cnt, bukcnt, staging,
                                        ovf_cnt, ovf);
    scan_part_kernel<<<SCAN_BLK, 256, 0, stream>>>(deg_cnt, bukcnt, staging, blocksum,
                                                   dinv);
    scan_write_kernel<<<SCAN_BLK + NL, 256, 0, stream>>>(deg_cnt, blocksum, rowptr,
                                                         Ws, wfrag);
    // scatter (blocks 0..NBUK) runs concurrently with gemm layer 0 (remaining blocks)
    scatter_gemm_kernel<<<NBUK + 1 + NT, 256, 0, stream>>>(
        bukcnt, staging, ovf_cnt, ovf, rowptr, deg_cnt, csw,
        x, wfrag, dinv, t, accum + 0 * 128);
    gather_kernel<<<GB_BLOCKS, 256, 0, stream>>>(t, dinv, bs + 0 * DD, rowptr, csw, h,
                                                 accum + 0 * 128);

    for (int l = 1; l < NL; ++l) {
        gemm_kernel<<<NT, 256, 0, stream>>>(h, wfrag + (size_t)l * WFL, dinv,
                                            accum + (l - 1) * 128,
                                            gammas + (size_t)(l - 1) * DD,
                                            betas + (size_t)(l - 1) * DD,
                                            t, accum + l * 128);
        gather_kernel<<<GB_BLOCKS, 256, 0, stream>>>(t, dinv, bs + l * DD, rowptr, csw, h,
                                                     accum + l * 128);
    }

    pool_kernel<<<(NN + POOL_CHUNK - 1) / POOL_CHUNK, 256, 0, stream>>>(
        h, accum + 2 * 128, gammas + 2 * DD, betas + 2 * DD, batch, pool, counts,
        done, out);
}

// Round 9
// 488.500 us; speedup vs baseline: 1.0979x; 1.0979x over previous
//
#include <hip/hip_runtime.h>
#include <hip/hip_bf16.h>
#include <stdint.h>

typedef __hip_bfloat16 bf16;
typedef short bf16x8 __attribute__((ext_vector_type(8)));
typedef float f32x4 __attribute__((ext_vector_type(4)));

#define NN 100000
#define NE 1600000
#define DD 64
#define NL 3
#define NG 128
#define BN_EPS 1e-5f
#define SCAN_BLK 98  // ceil(NN / 1024)
#define TILE_ROWS 64
#define LSW 72       // padded bf16 row stride (144 B: 16B-aligned frags, <=2-way banks)
#define NT ((NN + TILE_ROWS - 1) / TILE_ROWS)  // 1563
#define GB_NODES 48
#define GB_BLOCKS ((NN + GB_NODES - 1) / GB_NODES)  // 2084
#define ECAP 1664    // staged padded edges per block (mean ~936)
#define CSW_CAP (NE + 7 * NN)  // padded CSR worst case (int slots)
#define WFL 8192     // shorts per layer of precomputed W fragments

// binned fill parameters
#define NBUK 391     // dst buckets of 256 nodes (d >> 8); 391*256 >= NN
#define BUK_CAP 4608 // mean 4096 + 8 sigma
#define OVF_CAP 8192
#define EPB 4096     // edges per bin block (16 per thread)
#define NBB ((NE + EPB - 1) / EPB)  // 391

__device__ __forceinline__ int ld_src(const int* ei, int e, int is32) {
    return is32 ? ei[e] : ei[2 * e];
}
__device__ __forceinline__ int ld_dst(const int* ei, int e, int is32) {
    return is32 ? ei[NE + e] : ei[2 * NE + 2 * e];
}
__device__ __forceinline__ int ld_batch(const int* b, int n, int is32) {
    return is32 ? b[n] : b[2 * n];
}
__device__ __forceinline__ float bf2f(unsigned short u) {
    return __uint_as_float(((unsigned int)u) << 16);
}
__device__ __forceinline__ unsigned short f2bf(float x) {
    bf16 b = __float2bfloat16(x);  // RNE
    return *reinterpret_cast<unsigned short*>(&b);
}
__device__ __forceinline__ void split_bf16(float x, unsigned short& hi, unsigned short& lo) {
    hi = f2bf(x);
    lo = f2bf(x - bf2f(hi));
}
__device__ __forceinline__ int pad8(int d) { return (d + 7) & ~7; }

// ---------------- bin pass 1: edges -> 391 dst-range buckets (self-detect int width) ----
__global__ __launch_bounds__(256) void bin_kernel(const int* __restrict__ ei,
                                                  int* __restrict__ deg_cnt,
                                                  int* __restrict__ bukcnt,
                                                  int* __restrict__ staging,
                                                  int* __restrict__ ovf_cnt,
                                                  int2* __restrict__ ovf) {
    __shared__ int hist[NBUK];
    __shared__ int base[NBUK];
    __shared__ int s_e;
    if (threadIdx.x == 0) s_e = 0;
    for (int i = threadIdx.x; i < NBUK; i += 256) hist[i] = 0;
    __syncthreads();
    // int32-vs-int64 detect: odd int-slots are src values (int32) or high words (int64)
    if (ei[2 * threadIdx.x + 1] != 0) atomicOr(&s_e, 1);
    __syncthreads();
    int is32 = s_e;

    int e0 = blockIdx.x * EPB;
    int myb[16], mypack[16], myidx[16];
#pragma unroll
    for (int k = 0; k < 16; ++k) {
        int e = e0 + k * 256 + threadIdx.x;
        myb[k] = -1;
        if (e < NE) {
            int s = ld_src(ei, e, is32), d = ld_dst(ei, e, is32);
            int b = d >> 8;
            myb[k] = b;
            mypack[k] = (s << 8) | (d & 255);
            myidx[k] = atomicAdd(&hist[b], 1);
        }
    }
    __syncthreads();
    for (int i = threadIdx.x; i < NBUK; i += 256)
        if (hist[i]) base[i] = atomicAdd(&bukcnt[i], hist[i]);
    __syncthreads();
#pragma unroll
    for (int k = 0; k < 16; ++k) {
        if (myb[k] >= 0) {
            int slot = base[myb[k]] + myidx[k];
            if (slot < BUK_CAP) {
                staging[myb[k] * BUK_CAP + slot] = mypack[k];
            } else {  // essentially-never overflow path (correctness guarantee)
                int d = (myb[k] << 8) | (mypack[k] & 255);
                atomicAdd(&deg_cnt[d], 1);  // overflow degree contribution
                int o = atomicAdd(ovf_cnt, 1);
                if (o < OVF_CAP) ovf[o] = make_int2(mypack[k] >> 8, d);
            }
        }
    }
}

// ---------------- scan phase 1: deg from staging hist (+ ovf), padded totals, dinv ------
__global__ __launch_bounds__(256) void scan_part_kernel(int* __restrict__ deg_cnt,
                                                        const int* __restrict__ bukcnt,
                                                        const int* __restrict__ staging,
                                                        int* __restrict__ blocksum,
                                                        float* __restrict__ dinv) {
    __shared__ int hist[1024];
    __shared__ int s[256];
    for (int i = threadIdx.x; i < 1024; i += 256) hist[i] = 0;
    __syncthreads();
    int b4 = blockIdx.x * 4;
#pragma unroll
    for (int j = 0; j < 4; ++j) {
        int bk = b4 + j;
        if (bk < NBUK) {
            int n = min(bukcnt[bk], BUK_CAP);
            const int* st = staging + bk * BUK_CAP;
            for (int i = threadIdx.x; i < n; i += 256)
                atomicAdd(&hist[(j << 8) | (st[i] & 255)], 1);
        }
    }
    __syncthreads();
    int base = blockIdx.x * 1024 + threadIdx.x * 4;
    int t = 0;
    if (base < NN) {  // NN % 4 == 0 -> whole int4 in-bounds
        int4 ov = *(const int4*)(deg_cnt + base);              // overflow counts (~0)
        int4 hv = *(const int4*)(hist + threadIdx.x * 4);      // local hist
        int4 v = make_int4(ov.x + hv.x, ov.y + hv.y, ov.z + hv.z, ov.w + hv.w);
        *(int4*)(deg_cnt + base) = v;                          // true degree (coalesced)
        t = pad8(v.x) + pad8(v.y) + pad8(v.z) + pad8(v.w);
        float4 dv = make_float4(rsqrtf((float)v.x + 1.f), rsqrtf((float)v.y + 1.f),
                                rsqrtf((float)v.z + 1.f), rsqrtf((float)v.w + 1.f));
        *(float4*)(dinv + base) = dv;  // +1 self-loop
    }
    s[threadIdx.x] = t;
    __syncthreads();
    for (int off = 128; off > 0; off >>= 1) {
        if (threadIdx.x < off) s[threadIdx.x] += s[threadIdx.x + off];
        __syncthreads();
    }
    if (threadIdx.x == 0) blocksum[blockIdx.x] = s[0];
}

// ---------------- scan phase 2 (+ piggybacked W-fragment prep in blocks >= SCAN_BLK) ----
__global__ __launch_bounds__(256) void scan_write_kernel(int* __restrict__ deg_cnt,
                                                         const int* __restrict__ blocksum,
                                                         int* __restrict__ rowptr,
                                                         const float* __restrict__ Ws,
                                                         unsigned short* __restrict__ wfrag) {
    if (blockIdx.x >= SCAN_BLK) {  // W-prep: split W into hi/lo fragments, once per layer
        int l = blockIdx.x - SCAN_BLK;  // 0..NL-1
        const float* W = Ws + (size_t)l * DD * DD;
        unsigned short* wf = wfrag + (size_t)l * WFL;
        for (int slot = threadIdx.x; slot < 512; slot += 256) {
            int lane = slot & 63, nt = (slot >> 6) & 3, ks = slot >> 8;
            int lr = lane & 15, lg = lane >> 4;
#pragma unroll
            for (int e = 0; e < 8; ++e) {
                float wval = W[(ks * 32 + lg * 8 + e) * DD + nt * 16 + lr];
                unsigned short hi, lo;
                split_bf16(wval, hi, lo);
                wf[((0 * 2 + ks) * 4 + nt) * 512 + lane * 8 + e] = hi;
                wf[((1 * 2 + ks) * 4 + nt) * 512 + lane * 8 + e] = lo;
            }
        }
        return;
    }
    __shared__ int sb[128];
    __shared__ int s[256];
    if (threadIdx.x < 128)
        sb[threadIdx.x] = (threadIdx.x < SCAN_BLK) ? blocksum[threadIdx.x] : 0;
    __syncthreads();
    for (int off = 1; off < 128; off <<= 1) {
        int a = 0;
        if (threadIdx.x < 128 && threadIdx.x >= off) a = sb[threadIdx.x - off];
        __syncthreads();
        if (threadIdx.x < 128) sb[threadIdx.x] += a;
        __syncthreads();
    }
    int blockpre = (blockIdx.x == 0) ? 0 : sb[blockIdx.x - 1];
    if (blockIdx.x == SCAN_BLK - 1 && threadIdx.x == 0)
        rowptr[NN] = sb[SCAN_BLK - 1];  // padded total

    int base = blockIdx.x * 1024 + threadIdx.x * 4;
    int4 v = make_int4(0, 0, 0, 0);
    if (base < NN) v = *(const int4*)(deg_cnt + base);
    int p0 = pad8(v.x), p1 = pad8(v.y), p2 = pad8(v.z), p3 = pad8(v.w);
    int t = p0 + p1 + p2 + p3;
    s[threadIdx.x] = t;
    for (int off = 1; off < 256; off <<= 1) {
        __syncthreads();
        int a = (threadIdx.x >= off) ? s[threadIdx.x - off] : 0;
        __syncthreads();
        s[threadIdx.x] += a;
    }
    __syncthreads();
    int pre = blockpre + s[threadIdx.x] - t;  // exclusive padded prefix
    if (base < NN) {
        rowptr[base] = pre;
        rowptr[base + 1] = pre + p0;
        rowptr[base + 2] = pre + p0 + p1;
        rowptr[base + 3] = pre + p0 + p1 + p2;
        *(int4*)(deg_cnt + base) = make_int4(0, 0, 0, 0);  // becomes scatter cursor
    }
}

// ---------------- bin pass 2: bucket -> CSR scatter; window is L2-resident ----------------
__global__ __launch_bounds__(256) void scatter_kernel(const int* __restrict__ bukcnt,
                                                      const int* __restrict__ staging,
                                                      const int* __restrict__ ovf_cnt,
                                                      const int2* __restrict__ ovf,
                                                      const int* __restrict__ rowptr,
                                                      int* __restrict__ cursor,
                                                      int* __restrict__ csw) {
    int b = blockIdx.x;
    if (b == NBUK) {
        int n = min(*ovf_cnt, OVF_CAP);
        for (int i = threadIdx.x; i < n; i += 256) {
            int2 e = ovf[i];
            int pos = rowptr[e.y] + atomicAdd(&cursor[e.y], 1);
            csw[pos] = (e.x + 1) << 7;
        }
        return;
    }
    int n = min(bukcnt[b], BUK_CAP);
    int nb = b << 8;
    const int* st = staging + b * BUK_CAP;
    for (int i = threadIdx.x; i < n; i += 256) {
        int v = st[i];
        int d = nb + (v & 255);
        int pos = rowptr[d] + atomicAdd(&cursor[d], 1);
        csw[pos] = ((v >> 8) + 1) << 7;  // byte offset from zero-row base
    }
}

// ---------------- gemm: MFMA bf16x3-split w/ precomputed W frags ----------------
__global__ __launch_bounds__(256) void gemm_kernel(const float* __restrict__ h,
                                                   const unsigned short* __restrict__ wf,
                                                   const float* __restrict__ dinv,
                                                   const float* __restrict__ accum_prev,
                                                   const float* __restrict__ gamma,
                                                   const float* __restrict__ beta,
                                                   int use_bn, float alpha,
                                                   bf16* __restrict__ t,
                                                   float* __restrict__ accum_l) {
    if (blockIdx.x == 0 && threadIdx.x < 128) accum_l[threadIdx.x] = 0.f;

    __shared__ unsigned short ls_hi[TILE_ROWS * LSW];  // 9216 B (also epilogue repack)
    __shared__ unsigned short ls_lo[TILE_ROWS * LSW];  // 9216 B
    __shared__ float ssc[DD], ssh[DD], sdinv[TILE_ROWS];
    int tid = threadIdx.x;
    if (tid < 64) {
        if (use_bn) {
            float S = accum_prev[tid], Q = accum_prev[64 + tid];
            float mean = S / (float)NN;
            float var = fmaxf(Q / (float)NN - mean * mean, 0.f);
            float sc = gamma[tid] * rsqrtf(var + BN_EPS);
            ssc[tid] = sc;
            ssh[tid] = beta[tid] - mean * sc;
        } else {
            ssc[tid] = 1.f;
            ssh[tid] = 0.f;
        }
    }

    int lane = tid & 63;
    int wv = tid >> 6;   // wave 0..3 -> rows wv*16..wv*16+15
    int lr = lane & 15;  // row-in-tile / col-in-tile
    int lg = lane >> 4;  // k-group 0..3

    // B fragments: precomputed hi/lo splits, coalesced 16B loads
    bf16x8 bhi[2][4], blo[2][4];
#pragma unroll
    for (int ks = 0; ks < 2; ++ks)
#pragma unroll
        for (int nt = 0; nt < 4; ++nt) {
            bhi[ks][nt] = *(const bf16x8*)(wf + ((0 * 2 + ks) * 4 + nt) * 512 + lane * 8);
            blo[ks][nt] = *(const bf16x8*)(wf + ((1 * 2 + ks) * 4 + nt) * 512 + lane * 8);
        }
    __syncthreads();  // ssc/ssh ready

    for (int tile = blockIdx.x; tile < NT; tile += gridDim.x) {
        int row0 = tile * TILE_ROWS;
        int nrows = min(TILE_ROWS, NN - row0);
        if (tid < 64) sdinv[tid] = (row0 + tid < NN) ? dinv[row0 + tid] : 0.f;
        // stage activated tile as hi/lo bf16
#pragma unroll
        for (int it = 0; it < 4; ++it) {
            int flat = (tid + it * 256) * 4;  // 0..16380
            int gflat = row0 * DD + flat;
            if (gflat < NN * DD) {
                float4 hv = *(const float4*)(h + gflat);
                int c0 = flat & 63;
                float4 s4 = *(const float4*)(ssc + c0);
                float4 b4 = *(const float4*)(ssh + c0);
                float x0 = hv.x * s4.x + b4.x;
                float x1 = hv.y * s4.y + b4.y;
                float x2 = hv.z * s4.z + b4.z;
                float x3 = hv.w * s4.w + b4.w;
                x0 = fmaxf(x0, x0 * alpha);
                x1 = fmaxf(x1, x1 * alpha);
                x2 = fmaxf(x2, x2 * alpha);
                x3 = fmaxf(x3, x3 * alpha);
                unsigned short h0, l0, h1, l1, h2, l2, h3, l3;
                split_bf16(x0, h0, l0);
                split_bf16(x1, h1, l1);
                split_bf16(x2, h2, l2);
                split_bf16(x3, h3, l3);
                int row = flat >> 6;
                *(ushort4*)(ls_hi + row * LSW + c0) = make_ushort4(h0, h1, h2, h3);
                *(ushort4*)(ls_lo + row * LSW + c0) = make_ushort4(l0, l1, l2, l3);
            }
        }
        __syncthreads();

        f32x4 acc[4];
#pragma unroll
        for (int nt = 0; nt < 4; ++nt) acc[nt] = (f32x4){0.f, 0.f, 0.f, 0.f};

#pragma unroll
        for (int ks = 0; ks < 2; ++ks) {
            int aoff = (wv * 16 + lr) * LSW + ks * 32 + lg * 8;  // 16B-aligned
            bf16x8 a_hi = *(const bf16x8*)(ls_hi + aoff);
            bf16x8 a_lo = *(const bf16x8*)(ls_lo + aoff);
#pragma unroll
            for (int nt = 0; nt < 4; ++nt) {
                acc[nt] = __builtin_amdgcn_mfma_f32_16x16x32_bf16(a_hi, bhi[ks][nt],
                                                                  acc[nt], 0, 0, 0);
                acc[nt] = __builtin_amdgcn_mfma_f32_16x16x32_bf16(a_hi, blo[ks][nt],
                                                                  acc[nt], 0, 0, 0);
                acc[nt] = __builtin_amdgcn_mfma_f32_16x16x32_bf16(a_lo, bhi[ks][nt],
                                                                  acc[nt], 0, 0, 0);
            }
        }
        __syncthreads();  // all A-frag reads done; ls_hi reusable for repack

        // repack D*dinv -> bf16 tile in LDS, then coalesced store
#pragma unroll
        for (int nt = 0; nt < 4; ++nt)
#pragma unroll
            for (int rg = 0; rg < 4; ++rg) {
                int orow = wv * 16 + lg * 4 + rg;
                ls_hi[orow * LSW + nt * 16 + lr] = f2bf(acc[nt][rg] * sdinv[orow]);
            }
        __syncthreads();
#pragma unroll
        for (int it = 0; it < 2; ++it) {
            int flat8 = (tid + it * 256) * 8;  // 0..4088
            int row = flat8 >> 6, c = flat8 & 63;
            if (row < nrows) {
                uint4 v = *(const uint4*)(ls_hi + row * LSW + c);
                *(uint4*)((unsigned short*)t + (size_t)(row0 + row) * DD + c) = v;
            }
        }
        __syncthreads();  // before next tile overwrites ls
    }
}

// ---------------- gather: 4B edges, weightless adds, 4-node quad per wave ----------------
__device__ __forceinline__ void batch8(const int* __restrict__ ep, int j,
                                       const char* __restrict__ tbase, int f2,
                                       float& acc) {
    int4 a0 = *(const int4*)(ep + j);
    int4 a1 = *(const int4*)(ep + j + 4);
    unsigned short r[8];
    r[0] = *(const unsigned short*)(tbase + (unsigned)(a0.x + f2));
    r[1] = *(const unsigned short*)(tbase + (unsigned)(a0.y + f2));
    r[2] = *(const unsigned short*)(tbase + (unsigned)(a0.z + f2));
    r[3] = *(const unsigned short*)(tbase + (unsigned)(a0.w + f2));
    r[4] = *(const unsigned short*)(tbase + (unsigned)(a1.x + f2));
    r[5] = *(const unsigned short*)(tbase + (unsigned)(a1.y + f2));
    r[6] = *(const unsigned short*)(tbase + (unsigned)(a1.z + f2));
    r[7] = *(const unsigned short*)(tbase + (unsigned)(a1.w + f2));
    float s01 = bf2f(r[0]) + bf2f(r[1]), s23 = bf2f(r[2]) + bf2f(r[3]);
    float s45 = bf2f(r[4]) + bf2f(r[5]), s67 = bf2f(r[6]) + bf2f(r[7]);
    acc += (s01 + s23) + (s45 + s67);
}

__device__ __forceinline__ void batch8x2(const int* __restrict__ ep, int jA, int jB,
                                         const char* __restrict__ tbase, int f2,
                                         float& accA, float& accB) {
    int4 aA0 = *(const int4*)(ep + jA), aA1 = *(const int4*)(ep + jA + 4);
    int4 aB0 = *(const int4*)(ep + jB), aB1 = *(const int4*)(ep + jB + 4);
    unsigned short rA[8], rB[8];
    rA[0] = *(const unsigned short*)(tbase + (unsigned)(aA0.x + f2));
    rA[1] = *(const unsigned short*)(tbase + (unsigned)(aA0.y + f2));
    rA[2] = *(const unsigned short*)(tbase + (unsigned)(aA0.z + f2));
    rA[3] = *(const unsigned short*)(tbase + (unsigned)(aA0.w + f2));
    rA[4] = *(const unsigned short*)(tbase + (unsigned)(aA1.x + f2));
    rA[5] = *(const unsigned short*)(tbase + (unsigned)(aA1.y + f2));
    rA[6] = *(const unsigned short*)(tbase + (unsigned)(aA1.z + f2));
    rA[7] = *(const unsigned short*)(tbase + (unsigned)(aA1.w + f2));
    rB[0] = *(const unsigned short*)(tbase + (unsigned)(aB0.x + f2));
    rB[1] = *(const unsigned short*)(tbase + (unsigned)(aB0.y + f2));
    rB[2] = *(const unsigned short*)(tbase + (unsigned)(aB0.z + f2));
    rB[3] = *(const unsigned short*)(tbase + (unsigned)(aB0.w + f2));
    rB[4] = *(const unsigned short*)(tbase + (unsigned)(aB1.x + f2));
    rB[5] = *(const unsigned short*)(tbase + (unsigned)(aB1.y + f2));
    rB[6] = *(const unsigned short*)(tbase + (unsigned)(aB1.z + f2));
    rB[7] = *(const unsigned short*)(tbase + (unsigned)(aB1.w + f2));
    float sA01 = bf2f(rA[0]) + bf2f(rA[1]), sA23 = bf2f(rA[2]) + bf2f(rA[3]);
    float sA45 = bf2f(rA[4]) + bf2f(rA[5]), sA67 = bf2f(rA[6]) + bf2f(rA[7]);
    accA += (sA01 + sA23) + (sA45 + sA67);
    float sB01 = bf2f(rB[0]) + bf2f(rB[1]), sB23 = bf2f(rB[2]) + bf2f(rB[3]);
    float sB45 = bf2f(rB[4]) + bf2f(rB[5]), sB67 = bf2f(rB[6]) + bf2f(rB[7]);
    accB += (sB01 + sB23) + (sB45 + sB67);
}

__device__ __forceinline__ void batch8x4(const int* __restrict__ ep, int jA, int jB,
                                         int jC, int jD,
                                         const char* __restrict__ tbase, int f2,
                                         float& accA, float& accB, float& accC,
                                         float& accD) {
    int4 aA0 = *(const int4*)(ep + jA), aA1 = *(const int4*)(ep + jA + 4);
    int4 aB0 = *(const int4*)(ep + jB), aB1 = *(const int4*)(ep + jB + 4);
    int4 aC0 = *(const int4*)(ep + jC), aC1 = *(const int4*)(ep + jC + 4);
    int4 aD0 = *(const int4*)(ep + jD), aD1 = *(const int4*)(ep + jD + 4);
    unsigned short rA[8], rB[8], rC[8], rD[8];
    rA[0] = *(const unsigned short*)(tbase + (unsigned)(aA0.x + f2));
    rA[1] = *(const unsigned short*)(tbase + (unsigned)(aA0.y + f2));
    rA[2] = *(const unsigned short*)(tbase + (unsigned)(aA0.z + f2));
    rA[3] = *(const unsigned short*)(tbase + (unsigned)(aA0.w + f2));
    rA[4] = *(const unsigned short*)(tbase + (unsigned)(aA1.x + f2));
    rA[5] = *(const unsigned short*)(tbase + (unsigned)(aA1.y + f2));
    rA[6] = *(const unsigned short*)(tbase + (unsigned)(aA1.z + f2));
    rA[7] = *(const unsigned short*)(tbase + (unsigned)(aA1.w + f2));
    rB[0] = *(const unsigned short*)(tbase + (unsigned)(aB0.x + f2));
    rB[1] = *(const unsigned short*)(tbase + (unsigned)(aB0.y + f2));
    rB[2] = *(const unsigned short*)(tbase + (unsigned)(aB0.z + f2));
    rB[3] = *(const unsigned short*)(tbase + (unsigned)(aB0.w + f2));
    rB[4] = *(const unsigned short*)(tbase + (unsigned)(aB1.x + f2));
    rB[5] = *(const unsigned short*)(tbase + (unsigned)(aB1.y + f2));
    rB[6] = *(const unsigned short*)(tbase + (unsigned)(aB1.z + f2));
    rB[7] = *(const unsigned short*)(tbase + (unsigned)(aB1.w + f2));
    rC[0] = *(const unsigned short*)(tbase + (unsigned)(aC0.x + f2));
    rC[1] = *(const unsigned short*)(tbase + (unsigned)(aC0.y + f2));
    rC[2] = *(const unsigned short*)(tbase + (unsigned)(aC0.z + f2));
    rC[3] = *(const unsigned short*)(tbase + (unsigned)(aC0.w + f2));
    rC[4] = *(const unsigned short*)(tbase + (unsigned)(aC1.x + f2));
    rC[5] = *(const unsigned short*)(tbase + (unsigned)(aC1.y + f2));
    rC[6] = *(const unsigned short*)(tbase + (unsigned)(aC1.z + f2));
    rC[7] = *(const unsigned short*)(tbase + (unsigned)(aC1.w + f2));
    rD[0] = *(const unsigned short*)(tbase + (unsigned)(aD0.x + f2));
    rD[1] = *(const unsigned short*)(tbase + (unsigned)(aD0.y + f2));
    rD[2] = *(const unsigned short*)(tbase + (unsigned)(aD0.z + f2));
    rD[3] = *(const unsigned short*)(tbase + (unsigned)(aD0.w + f2));
    rD[4] = *(const unsigned short*)(tbase + (unsigned)(aD1.x + f2));
    rD[5] = *(const unsigned short*)(tbase + (unsigned)(aD1.y + f2));
    rD[6] = *(const unsigned short*)(tbase + (unsigned)(aD1.z + f2));
    rD[7] = *(const unsigned short*)(tbase + (unsigned)(aD1.w + f2));
    float sA01 = bf2f(rA[0]) + bf2f(rA[1]), sA23 = bf2f(rA[2]) + bf2f(rA[3]);
    float sA45 = bf2f(rA[4]) + bf2f(rA[5]), sA67 = bf2f(rA[6]) + bf2f(rA[7]);
    accA += (sA01 + sA23) + (sA45 + sA67);
    float sB01 = bf2f(rB[0]) + bf2f(rB[1]), sB23 = bf2f(rB[2]) + bf2f(rB[3]);
    float sB45 = bf2f(rB[4]) + bf2f(rB[5]), sB67 = bf2f(rB[6]) + bf2f(rB[7]);
    accB += (sB01 + sB23) + (sB45 + sB67);
    float sC01 = bf2f(rC[0]) + bf2f(rC[1]), sC23 = bf2f(rC[2]) + bf2f(rC[3]);
    float sC45 = bf2f(rC[4]) + bf2f(rC[5]), sC67 = bf2f(rC[6]) + bf2f(rC[7]);
    accC += (sC01 + sC23) + (sC45 + sC67);
    float sD01 = bf2f(rD[0]) + bf2f(rD[1]), sD23 = bf2f(rD[2]) + bf2f(rD[3]);
    float sD45 = bf2f(rD[4]) + bf2f(rD[5]), sD67 = bf2f(rD[6]) + bf2f(rD[7]);
    accD += (sD01 + sD23) + (sD45 + sD67);
}

// drain chain: x4 while all alive, then every x2 pairing, then singles.
// All bounds are wave-uniform (per-node), so branches don't diverge.
__device__ __forceinline__ void run_quad(const int* __restrict__ ep,
                                         const char* __restrict__ tbase, int f2,
                                         int jA, int eA, int jB, int eB,
                                         int jC, int eC, int jD, int eD,
                                         float& accA, float& accB, float& accC,
                                         float& accD) {
    while (jA < eA && jB < eB && jC < eC && jD < eD) {
        batch8x4(ep, jA, jB, jC, jD, tbase, f2, accA, accB, accC, accD);
        jA += 8; jB += 8; jC += 8; jD += 8;
    }
    while (jA < eA && jB < eB) { batch8x2(ep, jA, jB, tbase, f2, accA, accB); jA += 8; jB += 8; }
    while (jC < eC && jD < eD) { batch8x2(ep, jC, jD, tbase, f2, accC, accD); jC += 8; jD += 8; }
    while (jA < eA && jC < eC) { batch8x2(ep, jA, jC, tbase, f2, accA, accC); jA += 8; jC += 8; }
    while (jA < eA && jD < eD) { batch8x2(ep, jA, jD, tbase, f2, accA, accD); jA += 8; jD += 8; }
    while (jB < eB && jC < eC) { batch8x2(ep, jB, jC, tbase, f2, accB, accC); jB += 8; jC += 8; }
    while (jB < eB && jD < eD) { batch8x2(ep, jB, jD, tbase, f2, accB, accD); jB += 8; jD += 8; }
    while (jA < eA) { batch8(ep, jA, tbase, f2, accA); jA += 8; }
    while (jB < eB) { batch8(ep, jB, tbase, f2, accB); jB += 8; }
    while (jC < eC) { batch8(ep, jC, tbase, f2, accC); jC += 8; }
    while (jD < eD) { batch8(ep, jD, tbase, f2, accD); jD += 8; }
}

__global__ __launch_bounds__(256) void gather_kernel(const bf16* __restrict__ t,
                                                     const float* __restrict__ dinv,
                                                     const float* __restrict__ bias,
                                                     const int* __restrict__ rowptr,
                                                     const int* __restrict__ csw,
                                                     float* __restrict__ h,
                                                     float* __restrict__ accum_l) {
    __shared__ __attribute__((aligned(16))) int se[ECAP];  // 6.5 KB staged byte-offsets
    __shared__ int srp[GB_NODES + 1];  // staged rowptr slice
    __shared__ float s_sum[256], s_sq[256];

    int f = threadIdx.x & 63;
    int wv = threadIdx.x >> 6;
    int nb0 = blockIdx.x * GB_NODES;
    int nloc = min(GB_NODES, NN - nb0);  // 48 or 16; always multiple of 4

    for (int i = threadIdx.x; i <= nloc; i += 256) srp[i] = rowptr[nb0 + i];
    __syncthreads();
    int ebase = srp[0];
    int nE = srp[nloc] - ebase;  // multiple of 8
    bool staged = (nE <= ECAP);
    if (staged) {  // vectorized stage: ebase, nE multiples of 8 -> int4 aligned
        for (int i = threadIdx.x * 4; i < nE; i += 1024)
            *(int4*)(se + i) = *(const int4*)(csw + ebase + i);
    }
    __syncthreads();

    const char* tbase = (const char*)t - 128;  // zero-row base (pad slot 0 -> zeros)
    int f2 = f * 2;
    const unsigned short* tf = (const unsigned short*)t + f;
    float bb = bias[f];
    float sum = 0.f, sq = 0.f;

    for (int q = wv; 4 * q < nloc; q += 4) {  // wave handles node quad 4q..4q+3
        int d0 = 4 * q;
        int nA = nb0 + d0, nB = nA + 1, nC = nA + 2, nD = nA + 3;
        // init with self-loop t'[n]; dinv[n] applied at the end
        float accA = bf2f(tf[(size_t)nA * DD]);
        float accB = bf2f(tf[(size_t)nB * DD]);
        float accC = bf2f(tf[(size_t)nC * DD]);
        float accD = bf2f(tf[(size_t)nD * DD]);
        int jA = srp[d0] - ebase, eA = srp[d0 + 1] - ebase;  // multiples of 8
        int jB = eA, eB = srp[d0 + 2] - ebase;
        int jC = eB, eC = srp[d0 + 3] - ebase;
        int jD = eC, eD = srp[d0 + 4] - ebase;

        if (staged)
            run_quad(se, tbase, f2, jA, eA, jB, eB, jC, eC, jD, eD, accA, accB, accC, accD);
        else  // overflow block (vanishingly rare): csw from global
            run_quad(csw + ebase, tbase, f2, jA, eA, jB, eB, jC, eC, jD, eD,
                     accA, accB, accC, accD);

        float diA = dinv[nA], diB = dinv[nB], diC = dinv[nC], diD = dinv[nD];
        accA = accA * diA + bb;
        accB = accB * diB + bb;
        accC = accC * diC + bb;
        accD = accD * diD + bb;
        h[(size_t)nA * DD + f] = accA;
        h[(size_t)nB * DD + f] = accB;
        h[(size_t)nC * DD + f] = accC;
        h[(size_t)nD * DD + f] = accD;
        sum += accA + accB + accC + accD;
        sq += accA * accA + accB * accB + accC * accC + accD * accD;
    }
    s_sum[threadIdx.x] = sum;
    s_sq[threadIdx.x] = sq;
    __syncthreads();
    if (threadIdx.x < 64) {
        sum = s_sum[f] + s_sum[64 + f] + s_sum[128 + f] + s_sum[192 + f];
        sq = s_sq[f] + s_sq[64 + f] + s_sq[128 + f] + s_sq[192 + f];
        atomicAdd(&accum_l[f], sum);
        atomicAdd(&accum_l[64 + f], sq);
    }
}

// ---------------- pool: inline BN finalize(layer3) + ReLU + mean-pool + counts ----------------
#define POOL_CHUNK 128
__global__ __launch_bounds__(256) void pool_kernel(const float* __restrict__ hraw,
                                                   const float* __restrict__ accum_l,
                                                   const float* __restrict__ gamma,
                                                   const float* __restrict__ beta,
                                                   const int* __restrict__ batch,
                                                   float* __restrict__ pool,
                                                   float* __restrict__ counts) {
    __shared__ float ssc[64], ssh[64];
    __shared__ int s_b;
    if (threadIdx.x == 0) s_b = 0;
    if (threadIdx.x < 64) {
        float S = accum_l[threadIdx.x], Q = accum_l[64 + threadIdx.x];
        float mean = S / (float)NN;
        float var = fmaxf(Q / (float)NN - mean * mean, 0.f);
        float sc = gamma[threadIdx.x] * rsqrtf(var + BN_EPS);
        ssc[threadIdx.x] = sc;
        ssh[threadIdx.x] = beta[threadIdx.x] - mean * sc;
    }
    __syncthreads();
    // batch width detect: tail odd slots are values ~127 (int32) or high words (int64)
    if (batch[NN - 1024 + 2 * threadIdx.x + 1] != 0) atomicOr(&s_b, 1);
    __syncthreads();
    int is32 = s_b;
    int f = threadIdx.x & 63, rg = threadIdx.x >> 6;
    float sc = ssc[f], sh = ssh[f];
    int base = blockIdx.x * POOL_CHUNK;
    float acc = 0.f, cnt = 0.f;
    int cur = -1;
    for (int i = rg; i < POOL_CHUNK; i += 4) {
        int n = base + i;
        if (n >= NN) break;
        int g = ld_batch(batch, n, is32);
        if (g != cur) {
            if (cur >= 0) {
                atomicAdd(&pool[cur * DD + f], acc);
                if (f == 0) atomicAdd(&counts[cur], cnt);
            }
            acc = 0.f;
            cnt = 0.f;
            cur = g;
        }
        acc += fmaxf(hraw[(size_t)n * DD + f] * sc + sh, 0.f);
        cnt += 1.f;
    }
    if (cur >= 0) {
        atomicAdd(&pool[cur * DD + f], acc);
        if (f == 0) atomicAdd(&counts[cur], cnt);
    }
}

__global__ __launch_bounds__(256) void final_kernel(const float* __restrict__ pool,
                                                    const float* __restrict__ counts,
                                                    float* __restrict__ out) {
    int i = blockIdx.x * 256 + threadIdx.x;
    if (i < NG * DD) {
        int g = i >> 6;
        out[i] = pool[i] / fmaxf(counts[g], 1.0f);
    }
}

extern "C" void kernel_launch(void* const* d_in, const int* in_sizes, int n_in,
                              void* d_out, int out_size, void* d_ws, size_t ws_size,
                              hipStream_t stream) {
    const float* x = (const float*)d_in[0];       // [NN, DD] f32
    const int* edge_index = (const int*)d_in[1];  // [2, NE] int (width detected)
    const int* batch = (const int*)d_in[2];       // [NN] int (width detected)
    const float* Ws = (const float*)d_in[3];      // [3,64,64]
    const float* bs = (const float*)d_in[4];      // [3,64]
    const float* gammas = (const float*)d_in[5];  // [3,64]
    const float* betas = (const float*)d_in[6];   // [3,64]
    float* out = (float*)d_out;                   // [NG, DD]

    // workspace layout
    float* h = (float*)d_ws;                    // 25.6 MB (bin staging before gather 0)
    bf16* zrow = (bf16*)(h + (size_t)NN * DD);  // 128 B zero row (pad-slot target)
    bf16* t = zrow + DD;                        // 12.8 MB (t' = scaled transform)
    int* csw = (int*)(t + (size_t)NN * DD);     // CSW_CAP int (9.2 MB, padded CSR)
    float* dinv = (float*)(csw + CSW_CAP);      // 100,000 f
    int* deg_cnt = (int*)(dinv + NN);           // 100,000 i (deg, then scatter cursor)
    float* pool = (float*)(deg_cnt + NN);       // 8192 f
    float* counts = pool + NG * DD;             // 128 f
    int* bukcnt = (int*)(counts + NG);          // NBUK i
    int* ovf_cnt = bukcnt + NBUK;               // 1 i
    int* rowptr = ovf_cnt + 1;                  // 100,001 i (padded CSR offsets)
    float* accum = (float*)(rowptr + NN + 1);   // NL*128 f (BN sum/sumsq per layer)
    int* blocksum = (int*)(accum + NL * 128);   // 128 i
    unsigned short* wfrag =                     // NL*WFL shorts (48 KB), 16B-aligned
        (unsigned short*)(((uintptr_t)(blocksum + 128) + 15) & ~(uintptr_t)15);
    int2* ovf = (int2*)(wfrag + (size_t)NL * WFL);  // OVF_CAP int2 (16B-aligned)
    int* staging = (int*)h;                     // NBUK*BUK_CAP ints = 7.2 MB

    // one memset covers deg_cnt + pool + counts + bukcnt + ovf_cnt (contiguous)
    hipMemsetAsync(deg_cnt, 0, (NN + NG * DD + NG + NBUK + 1) * sizeof(int), stream);
    hipMemsetAsync(csw, 0, (size_t)CSW_CAP * sizeof(int), stream);  // pads -> zero-row
    hipMemsetAsync(zrow, 0, DD * sizeof(bf16), stream);

    bin_kernel<<<NBB, 256, 0, stream>>>(edge_index, deg_cnt, bukcnt, staging,
                                        ovf_cnt, ovf);
    scan_part_kernel<<<SCAN_BLK, 256, 0, stream>>>(deg_cnt, bukcnt, staging, blocksum,
                                                   dinv);
    scan_write_kernel<<<SCAN_BLK + NL, 256, 0, stream>>>(deg_cnt, blocksum, rowptr,
                                                         Ws, wfrag);
    scatter_kernel<<<NBUK + 1, 256, 0, stream>>>(bukcnt, staging, ovf_cnt, ovf, rowptr,
                                                 deg_cnt, csw);

    for (int l = 0; l < NL; ++l) {
        const float* hin = (l == 0) ? x : h;
        float alpha = (l == 0) ? 1.0f : 0.0f;  // identity vs ReLU on input transform
        gemm_kernel<<<NT, 256, 0, stream>>>(hin, wfrag + (size_t)l * WFL, dinv,
                                            accum + (l - 1 >= 0 ? l - 1 : 0) * 128,
                                            gammas + (size_t)(l - 1 >= 0 ? l - 1 : 0) * DD,
                                            betas + (size_t)(l - 1 >= 0 ? l - 1 : 0) * DD,
                                            (l > 0) ? 1 : 0, alpha, t, accum + l * 128);
        gather_kernel<<<GB_BLOCKS, 256, 0, stream>>>(t, dinv, bs + l * DD, rowptr, csw, h,
                                                     accum + l * 128);
    }

    pool_kernel<<<(NN + POOL_CHUNK - 1) / POOL_CHUNK, 256, 0, stream>>>(
        h, accum + 2 * 128, gammas + 2 * DD, betas + 2 * DD, batch, pool, counts);
    final_kernel<<<(NG * DD + 255) / 256, 256, 0, stream>>>(pool, counts, out);
}

// Round 10
// 486.885 us; speedup vs baseline: 1.1016x; 1.0033x over previous
//
#include <hip/hip_runtime.h>
#include <hip/hip_bf16.h>
#include <stdint.h>

typedef __hip_bfloat16 bf16;
typedef short bf16x8 __attribute__((ext_vector_type(8)));
typedef float f32x4 __attribute__((ext_vector_type(4)));

#define NN 100000
#define NE 1600000
#define DD 64
#define NL 3
#define NG 128
#define BN_EPS 1e-5f
#define SCAN_BLK 98  // ceil(NN / 1024)
#define TILE_ROWS 64
#define LSW 72       // padded bf16 row stride (144 B: 16B-aligned frags, <=2-way banks)
#define NT ((NN + TILE_ROWS - 1) / TILE_ROWS)  // 1563
#define GB_NODES 48
#define GB_BLOCKS ((NN + GB_NODES - 1) / GB_NODES)  // 2084
#define ECAP 1664    // staged padded edges per block (mean ~936)
#define CSW_CAP (NE + 7 * NN)  // padded CSR worst case (int slots)
#define WFL 8192     // shorts per layer of precomputed W fragments

// binned fill parameters
#define NBUK 391     // dst buckets of 256 nodes (d >> 8); 391*256 >= NN
#define BUK_CAP 4608 // mean 4096 + 8 sigma
#define OVF_CAP 8192
#define EPB 4096     // edges per bin block (16 per thread)
#define NBB ((NE + EPB - 1) / EPB)  // 391

__device__ __forceinline__ int ld_batch(const int* b, int n, int is32) {
    return is32 ? b[n] : b[2 * n];
}
__device__ __forceinline__ float bf2f(unsigned short u) {
    return __uint_as_float(((unsigned int)u) << 16);
}
__device__ __forceinline__ unsigned short f2bf(float x) {
    bf16 b = __float2bfloat16(x);  // RNE
    return *reinterpret_cast<unsigned short*>(&b);
}
__device__ __forceinline__ void split_bf16(float x, unsigned short& hi, unsigned short& lo) {
    hi = f2bf(x);
    lo = f2bf(x - bf2f(hi));
}
__device__ __forceinline__ int pad8(int d) { return (d + 7) & ~7; }

// ---------------- bin pass 1: edges -> 391 dst-range buckets ----------------
// v16: int4-vectorized edge loads (full line utilization on both src/dst streams;
// int64 path was 2x overfetch with stride-8B scalar loads). Invalid slot: dv = -256.
__global__ __launch_bounds__(256) void bin_kernel(const int* __restrict__ ei,
                                                  int* __restrict__ deg_cnt,
                                                  int* __restrict__ bukcnt,
                                                  int* __restrict__ staging,
                                                  int* __restrict__ ovf_cnt,
                                                  int2* __restrict__ ovf) {
    __shared__ int hist[NBUK];
    __shared__ int base[NBUK];
    __shared__ int s_e;
    if (threadIdx.x == 0) s_e = 0;
    for (int i = threadIdx.x; i < NBUK; i += 256) hist[i] = 0;
    __syncthreads();
    // int32-vs-int64 detect: odd int-slots are src values (int32) or high words (int64)
    if (ei[2 * threadIdx.x + 1] != 0) atomicOr(&s_e, 1);
    __syncthreads();
    int is32 = s_e;

    int e0 = blockIdx.x * EPB;
    int sv[16], dv[16], myidx[16];
    if (!is32) {  // int64: int4 covers 2 edges (srcs at .x/.z, same for dsts)
#pragma unroll
        for (int k2 = 0; k2 < 8; ++k2) {
            int eb = e0 + k2 * 512 + threadIdx.x * 2;  // even; NE even -> pair in-bounds
            if (eb < NE) {
                int4 s4 = *(const int4*)(ei + 2 * eb);           // 16B-aligned (8*eb)
                int4 d4 = *(const int4*)(ei + 2 * NE + 2 * eb);  // NE even -> aligned
                sv[2 * k2] = s4.x;
                dv[2 * k2] = d4.x;
                sv[2 * k2 + 1] = s4.z;
                dv[2 * k2 + 1] = d4.z;
            } else {
                dv[2 * k2] = -256;
                dv[2 * k2 + 1] = -256;
            }
        }
    } else {  // int32: int4 covers 4 edges
#pragma unroll
        for (int k4 = 0; k4 < 4; ++k4) {
            int eb = e0 + k4 * 1024 + threadIdx.x * 4;  // mult of 4; NE%4==0
            if (eb < NE) {
                int4 s4 = *(const int4*)(ei + eb);
                int4 d4 = *(const int4*)(ei + NE + eb);
                sv[4 * k4] = s4.x;
                dv[4 * k4] = d4.x;
                sv[4 * k4 + 1] = s4.y;
                dv[4 * k4 + 1] = d4.y;
                sv[4 * k4 + 2] = s4.z;
                dv[4 * k4 + 2] = d4.z;
                sv[4 * k4 + 3] = s4.w;
                dv[4 * k4 + 3] = d4.w;
            } else {
                dv[4 * k4] = -256;
                dv[4 * k4 + 1] = -256;
                dv[4 * k4 + 2] = -256;
                dv[4 * k4 + 3] = -256;
            }
        }
    }
#pragma unroll
    for (int k = 0; k < 16; ++k) {
        int b = dv[k] >> 8;
        if (b >= 0) myidx[k] = atomicAdd(&hist[b], 1);
    }
    __syncthreads();
    for (int i = threadIdx.x; i < NBUK; i += 256)
        if (hist[i]) base[i] = atomicAdd(&bukcnt[i], hist[i]);
    __syncthreads();
#pragma unroll
    for (int k = 0; k < 16; ++k) {
        int b = dv[k] >> 8;
        if (b >= 0) {
            int slot = base[b] + myidx[k];
            int pack = (sv[k] << 8) | (dv[k] & 255);
            if (slot < BUK_CAP) {
                staging[b * BUK_CAP + slot] = pack;
            } else {  // essentially-never overflow path (correctness guarantee)
                int d = dv[k];
                atomicAdd(&deg_cnt[d], 1);  // overflow degree contribution
                int o = atomicAdd(ovf_cnt, 1);
                if (o < OVF_CAP) ovf[o] = make_int2(sv[k], d);
            }
        }
    }
}

// ---------------- scan phase 1: deg from staging hist (+ ovf), padded totals, dinv ------
__global__ __launch_bounds__(256) void scan_part_kernel(int* __restrict__ deg_cnt,
                                                        const int* __restrict__ bukcnt,
                                                        const int* __restrict__ staging,
                                                        int* __restrict__ blocksum,
                                                        float* __restrict__ dinv) {
    __shared__ int hist[1024];
    __shared__ int s[256];
    for (int i = threadIdx.x; i < 1024; i += 256) hist[i] = 0;
    __syncthreads();
    int b4 = blockIdx.x * 4;
#pragma unroll
    for (int j = 0; j < 4; ++j) {
        int bk = b4 + j;
        if (bk < NBUK) {
            int n = min(bukcnt[bk], BUK_CAP);
            const int* st = staging + bk * BUK_CAP;
            for (int i = threadIdx.x; i < n; i += 256)
                atomicAdd(&hist[(j << 8) | (st[i] & 255)], 1);
        }
    }
    __syncthreads();
    int base = blockIdx.x * 1024 + threadIdx.x * 4;
    int t = 0;
    if (base < NN) {  // NN % 4 == 0 -> whole int4 in-bounds
        int4 ov = *(const int4*)(deg_cnt + base);              // overflow counts (~0)
        int4 hv = *(const int4*)(hist + threadIdx.x * 4);      // local hist
        int4 v = make_int4(ov.x + hv.x, ov.y + hv.y, ov.z + hv.z, ov.w + hv.w);
        *(int4*)(deg_cnt + base) = v;                          // true degree (coalesced)
        t = pad8(v.x) + pad8(v.y) + pad8(v.z) + pad8(v.w);
        float4 dv = make_float4(rsqrtf((float)v.x + 1.f), rsqrtf((float)v.y + 1.f),
                                rsqrtf((float)v.z + 1.f), rsqrtf((float)v.w + 1.f));
        *(float4*)(dinv + base) = dv;  // +1 self-loop
    }
    s[threadIdx.x] = t;
    __syncthreads();
    for (int off = 128; off > 0; off >>= 1) {
        if (threadIdx.x < off) s[threadIdx.x] += s[threadIdx.x + off];
        __syncthreads();
    }
    if (threadIdx.x == 0) blocksum[blockIdx.x] = s[0];
}

// ---------------- scan phase 2 (+ piggybacked W-fragment prep in blocks >= SCAN_BLK) ----
__global__ __launch_bounds__(256) void scan_write_kernel(int* __restrict__ deg_cnt,
                                                         const int* __restrict__ blocksum,
                                                         int* __restrict__ rowptr,
                                                         const float* __restrict__ Ws,
                                                         unsigned short* __restrict__ wfrag) {
    if (blockIdx.x >= SCAN_BLK) {  // W-prep: split W into hi/lo fragments, once per layer
        int l = blockIdx.x - SCAN_BLK;  // 0..NL-1
        const float* W = Ws + (size_t)l * DD * DD;
        unsigned short* wf = wfrag + (size_t)l * WFL;
        for (int slot = threadIdx.x; slot < 512; slot += 256) {
            int lane = slot & 63, nt = (slot >> 6) & 3, ks = slot >> 8;
            int lr = lane & 15, lg = lane >> 4;
#pragma unroll
            for (int e = 0; e < 8; ++e) {
                float wval = W[(ks * 32 + lg * 8 + e) * DD + nt * 16 + lr];
                unsigned short hi, lo;
                split_bf16(wval, hi, lo);
                wf[((0 * 2 + ks) * 4 + nt) * 512 + lane * 8 + e] = hi;
                wf[((1 * 2 + ks) * 4 + nt) * 512 + lane * 8 + e] = lo;
            }
        }
        return;
    }
    __shared__ int sb[128];
    __shared__ int s[256];
    if (threadIdx.x < 128)
        sb[threadIdx.x] = (threadIdx.x < SCAN_BLK) ? blocksum[threadIdx.x] : 0;
    __syncthreads();
    for (int off = 1; off < 128; off <<= 1) {
        int a = 0;
        if (threadIdx.x < 128 && threadIdx.x >= off) a = sb[threadIdx.x - off];
        __syncthreads();
        if (threadIdx.x < 128) sb[threadIdx.x] += a;
        __syncthreads();
    }
    int blockpre = (blockIdx.x == 0) ? 0 : sb[blockIdx.x - 1];
    if (blockIdx.x == SCAN_BLK - 1 && threadIdx.x == 0)
        rowptr[NN] = sb[SCAN_BLK - 1];  // padded total

    int base = blockIdx.x * 1024 + threadIdx.x * 4;
    int4 v = make_int4(0, 0, 0, 0);
    if (base < NN) v = *(const int4*)(deg_cnt + base);
    int p0 = pad8(v.x), p1 = pad8(v.y), p2 = pad8(v.z), p3 = pad8(v.w);
    int t = p0 + p1 + p2 + p3;
    s[threadIdx.x] = t;
    for (int off = 1; off < 256; off <<= 1) {
        __syncthreads();
        int a = (threadIdx.x >= off) ? s[threadIdx.x - off] : 0;
        __syncthreads();
        s[threadIdx.x] += a;
    }
    __syncthreads();
    int pre = blockpre + s[threadIdx.x] - t;  // exclusive padded prefix
    if (base < NN) {
        rowptr[base] = pre;
        rowptr[base + 1] = pre + p0;
        rowptr[base + 2] = pre + p0 + p1;
        rowptr[base + 3] = pre + p0 + p1 + p2;
        *(int4*)(deg_cnt + base) = make_int4(0, 0, 0, 0);  // becomes scatter cursor
    }
}

// ---------------- bin pass 2: bucket -> CSR scatter; window is L2-resident ----------------
__global__ __launch_bounds__(256) void scatter_kernel(const int* __restrict__ bukcnt,
                                                      const int* __restrict__ staging,
                                                      const int* __restrict__ ovf_cnt,
                                                      const int2* __restrict__ ovf,
                                                      const int* __restrict__ rowptr,
                                                      int* __restrict__ cursor,
                                                      int* __restrict__ csw) {
    int b = blockIdx.x;
    if (b == NBUK) {
        int n = min(*ovf_cnt, OVF_CAP);
        for (int i = threadIdx.x; i < n; i += 256) {
            int2 e = ovf[i];
            int pos = rowptr[e.y] + atomicAdd(&cursor[e.y], 1);
            csw[pos] = (e.x + 1) << 7;
        }
        return;
    }
    int n = min(bukcnt[b], BUK_CAP);
    int nb = b << 8;
    const int* st = staging + b * BUK_CAP;
    for (int i = threadIdx.x; i < n; i += 256) {
        int v = st[i];
        int d = nb + (v & 255);
        int pos = rowptr[d] + atomicAdd(&cursor[d], 1);
        csw[pos] = ((v >> 8) + 1) << 7;  // byte offset from zero-row base
    }
}

// ---------------- gemm: MFMA bf16x3-split w/ precomputed W frags ----------------
__global__ __launch_bounds__(256) void gemm_kernel(const float* __restrict__ h,
                                                   const unsigned short* __restrict__ wf,
                                                   const float* __restrict__ dinv,
                                                   const float* __restrict__ accum_prev,
                                                   const float* __restrict__ gamma,
                                                   const float* __restrict__ beta,
                                                   int use_bn, float alpha,
                                                   bf16* __restrict__ t,
                                                   float* __restrict__ accum_l) {
    if (blockIdx.x == 0 && threadIdx.x < 128) accum_l[threadIdx.x] = 0.f;

    __shared__ unsigned short ls_hi[TILE_ROWS * LSW];  // 9216 B (also epilogue repack)
    __shared__ unsigned short ls_lo[TILE_ROWS * LSW];  // 9216 B
    __shared__ float ssc[DD], ssh[DD], sdinv[TILE_ROWS];
    int tid = threadIdx.x;
    if (tid < 64) {
        if (use_bn) {
            float S = accum_prev[tid], Q = accum_prev[64 + tid];
            float mean = S / (float)NN;
            float var = fmaxf(Q / (float)NN - mean * mean, 0.f);
            float sc = gamma[tid] * rsqrtf(var + BN_EPS);
            ssc[tid] = sc;
            ssh[tid] = beta[tid] - mean * sc;
        } else {
            ssc[tid] = 1.f;
            ssh[tid] = 0.f;
        }
    }

    int lane = tid & 63;
    int wv = tid >> 6;   // wave 0..3 -> rows wv*16..wv*16+15
    int lr = lane & 15;  // row-in-tile / col-in-tile
    int lg = lane >> 4;  // k-group 0..3

    // B fragments: precomputed hi/lo splits, coalesced 16B loads
    bf16x8 bhi[2][4], blo[2][4];
#pragma unroll
    for (int ks = 0; ks < 2; ++ks)
#pragma unroll
        for (int nt = 0; nt < 4; ++nt) {
            bhi[ks][nt] = *(const bf16x8*)(wf + ((0 * 2 + ks) * 4 + nt) * 512 + lane * 8);
            blo[ks][nt] = *(const bf16x8*)(wf + ((1 * 2 + ks) * 4 + nt) * 512 + lane * 8);
        }
    __syncthreads();  // ssc/ssh ready

    for (int tile = blockIdx.x; tile < NT; tile += gridDim.x) {
        int row0 = tile * TILE_ROWS;
        int nrows = min(TILE_ROWS, NN - row0);
        if (tid < 64) sdinv[tid] = (row0 + tid < NN) ? dinv[row0 + tid] : 0.f;
        // stage activated tile as hi/lo bf16
#pragma unroll
        for (int it = 0; it < 4; ++it) {
            int flat = (tid + it * 256) * 4;  // 0..16380
            int gflat = row0 * DD + flat;
            if (gflat < NN * DD) {
                float4 hv = *(const float4*)(h + gflat);
                int c0 = flat & 63;
                float4 s4 = *(const float4*)(ssc + c0);
                float4 b4 = *(const float4*)(ssh + c0);
                float x0 = hv.x * s4.x + b4.x;
                float x1 = hv.y * s4.y + b4.y;
                float x2 = hv.z * s4.z + b4.z;
                float x3 = hv.w * s4.w + b4.w;
                x0 = fmaxf(x0, x0 * alpha);
                x1 = fmaxf(x1, x1 * alpha);
                x2 = fmaxf(x2, x2 * alpha);
                x3 = fmaxf(x3, x3 * alpha);
                unsigned short h0, l0, h1, l1, h2, l2, h3, l3;
                split_bf16(x0, h0, l0);
                split_bf16(x1, h1, l1);
                split_bf16(x2, h2, l2);
                split_bf16(x3, h3, l3);
                int row = flat >> 6;
                *(ushort4*)(ls_hi + row * LSW + c0) = make_ushort4(h0, h1, h2, h3);
                *(ushort4*)(ls_lo + row * LSW + c0) = make_ushort4(l0, l1, l2, l3);
            }
        }
        __syncthreads();

        f32x4 acc[4];
#pragma unroll
        for (int nt = 0; nt < 4; ++nt) acc[nt] = (f32x4){0.f, 0.f, 0.f, 0.f};

#pragma unroll
        for (int ks = 0; ks < 2; ++ks) {
            int aoff = (wv * 16 + lr) * LSW + ks * 32 + lg * 8;  // 16B-aligned
            bf16x8 a_hi = *(const bf16x8*)(ls_hi + aoff);
            bf16x8 a_lo = *(const bf16x8*)(ls_lo + aoff);
#pragma unroll
            for (int nt = 0; nt < 4; ++nt) {
                acc[nt] = __builtin_amdgcn_mfma_f32_16x16x32_bf16(a_hi, bhi[ks][nt],
                                                                  acc[nt], 0, 0, 0);
                acc[nt] = __builtin_amdgcn_mfma_f32_16x16x32_bf16(a_hi, blo[ks][nt],
                                                                  acc[nt], 0, 0, 0);
                acc[nt] = __builtin_amdgcn_mfma_f32_16x16x32_bf16(a_lo, bhi[ks][nt],
                                                                  acc[nt], 0, 0, 0);
            }
        }
        __syncthreads();  // all A-frag reads done; ls_hi reusable for repack

        // repack D*dinv -> bf16 tile in LDS, then coalesced store
#pragma unroll
        for (int nt = 0; nt < 4; ++nt)
#pragma unroll
            for (int rg = 0; rg < 4; ++rg) {
                int orow = wv * 16 + lg * 4 + rg;
                ls_hi[orow * LSW + nt * 16 + lr] = f2bf(acc[nt][rg] * sdinv[orow]);
            }
        __syncthreads();
#pragma unroll
        for (int it = 0; it < 2; ++it) {
            int flat8 = (tid + it * 256) * 8;  // 0..4088
            int row = flat8 >> 6, c = flat8 & 63;
            if (row < nrows) {
                uint4 v = *(const uint4*)(ls_hi + row * LSW + c);
                *(uint4*)((unsigned short*)t + (size_t)(row0 + row) * DD + c) = v;
            }
        }
        __syncthreads();  // before next tile overwrites ls
    }
}

// ---------------- gather: 4B edges, weightless adds, 4-node quad per wave ----------------
__device__ __forceinline__ void batch8(const int* __restrict__ ep, int j,
                                       const char* __restrict__ tbase, int f2,
                                       float& acc) {
    int4 a0 = *(const int4*)(ep + j);
    int4 a1 = *(const int4*)(ep + j + 4);
    unsigned short r[8];
    r[0] = *(const unsigned short*)(tbase + (unsigned)(a0.x + f2));
    r[1] = *(const unsigned short*)(tbase + (unsigned)(a0.y + f2));
    r[2] = *(const unsigned short*)(tbase + (unsigned)(a0.z + f2));
    r[3] = *(const unsigned short*)(tbase + (unsigned)(a0.w + f2));
    r[4] = *(const unsigned short*)(tbase + (unsigned)(a1.x + f2));
    r[5] = *(const unsigned short*)(tbase + (unsigned)(a1.y + f2));
    r[6] = *(const unsigned short*)(tbase + (unsigned)(a1.z + f2));
    r[7] = *(const unsigned short*)(tbase + (unsigned)(a1.w + f2));
    float s01 = bf2f(r[0]) + bf2f(r[1]), s23 = bf2f(r[2]) + bf2f(r[3]);
    float s45 = bf2f(r[4]) + bf2f(r[5]), s67 = bf2f(r[6]) + bf2f(r[7]);
    acc += (s01 + s23) + (s45 + s67);
}

__device__ __forceinline__ void batch8x2(const int* __restrict__ ep, int jA, int jB,
                                         const char* __restrict__ tbase, int f2,
                                         float& accA, float& accB) {
    int4 aA0 = *(const int4*)(ep + jA), aA1 = *(const int4*)(ep + jA + 4);
    int4 aB0 = *(const int4*)(ep + jB), aB1 = *(const int4*)(ep + jB + 4);
    unsigned short rA[8], rB[8];
    rA[0] = *(const unsigned short*)(tbase + (unsigned)(aA0.x + f2));
    rA[1] = *(const unsigned short*)(tbase + (unsigned)(aA0.y + f2));
    rA[2] = *(const unsigned short*)(tbase + (unsigned)(aA0.z + f2));
    rA[3] = *(const unsigned short*)(tbase + (unsigned)(aA0.w + f2));
    rA[4] = *(const unsigned short*)(tbase + (unsigned)(aA1.x + f2));
    rA[5] = *(const unsigned short*)(tbase + (unsigned)(aA1.y + f2));
    rA[6] = *(const unsigned short*)(tbase + (unsigned)(aA1.z + f2));
    rA[7] = *(const unsigned short*)(tbase + (unsigned)(aA1.w + f2));
    rB[0] = *(const unsigned short*)(tbase + (unsigned)(aB0.x + f2));
    rB[1] = *(const unsigned short*)(tbase + (unsigned)(aB0.y + f2));
    rB[2] = *(const unsigned short*)(tbase + (unsigned)(aB0.z + f2));
    rB[3] = *(const unsigned short*)(tbase + (unsigned)(aB0.w + f2));
    rB[4] = *(const unsigned short*)(tbase + (unsigned)(aB1.x + f2));
    rB[5] = *(const unsigned short*)(tbase + (unsigned)(aB1.y + f2));
    rB[6] = *(const unsigned short*)(tbase + (unsigned)(aB1.z + f2));
    rB[7] = *(const unsigned short*)(tbase + (unsigned)(aB1.w + f2));
    float sA01 = bf2f(rA[0]) + bf2f(rA[1]), sA23 = bf2f(rA[2]) + bf2f(rA[3]);
    float sA45 = bf2f(rA[4]) + bf2f(rA[5]), sA67 = bf2f(rA[6]) + bf2f(rA[7]);
    accA += (sA01 + sA23) + (sA45 + sA67);
    float sB01 = bf2f(rB[0]) + bf2f(rB[1]), sB23 = bf2f(rB[2]) + bf2f(rB[3]);
    float sB45 = bf2f(rB[4]) + bf2f(rB[5]), sB67 = bf2f(rB[6]) + bf2f(rB[7]);
    accB += (sB01 + sB23) + (sB45 + sB67);
}

__device__ __forceinline__ void batch8x4(const int* __restrict__ ep, int jA, int jB,
                                         int jC, int jD,
                                         const char* __restrict__ tbase, int f2,
                                         float& accA, float& accB, float& accC,
                                         float& accD) {
    int4 aA0 = *(const int4*)(ep + jA), aA1 = *(const int4*)(ep + jA + 4);
    int4 aB0 = *(const int4*)(ep + jB), aB1 = *(const int4*)(ep + jB + 4);
    int4 aC0 = *(const int4*)(ep + jC), aC1 = *(const int4*)(ep + jC + 4);
    int4 aD0 = *(const int4*)(ep + jD), aD1 = *(const int4*)(ep + jD + 4);
    unsigned short rA[8], rB[8], rC[8], rD[8];
    rA[0] = *(const unsigned short*)(tbase + (unsigned)(aA0.x + f2));
    rA[1] = *(const unsigned short*)(tbase + (unsigned)(aA0.y + f2));
    rA[2] = *(const unsigned short*)(tbase + (unsigned)(aA0.z + f2));
    rA[3] = *(const unsigned short*)(tbase + (unsigned)(aA0.w + f2));
    rA[4] = *(const unsigned short*)(tbase + (unsigned)(aA1.x + f2));
    rA[5] = *(const unsigned short*)(tbase + (unsigned)(aA1.y + f2));
    rA[6] = *(const unsigned short*)(tbase + (unsigned)(aA1.z + f2));
    rA[7] = *(const unsigned short*)(tbase + (unsigned)(aA1.w + f2));
    rB[0] = *(const unsigned short*)(tbase + (unsigned)(aB0.x + f2));
    rB[1] = *(const unsigned short*)(tbase + (unsigned)(aB0.y + f2));
    rB[2] = *(const unsigned short*)(tbase + (unsigned)(aB0.z + f2));
    rB[3] = *(const unsigned short*)(tbase + (unsigned)(aB0.w + f2));
    rB[4] = *(const unsigned short*)(tbase + (unsigned)(aB1.x + f2));
    rB[5] = *(const unsigned short*)(tbase + (unsigned)(aB1.y + f2));
    rB[6] = *(const unsigned short*)(tbase + (unsigned)(aB1.z + f2));
    rB[7] = *(const unsigned short*)(tbase + (unsigned)(aB1.w + f2));
    rC[0] = *(const unsigned short*)(tbase + (unsigned)(aC0.x + f2));
    rC[1] = *(const unsigned short*)(tbase + (unsigned)(aC0.y + f2));
    rC[2] = *(const unsigned short*)(tbase + (unsigned)(aC0.z + f2));
    rC[3] = *(const unsigned short*)(tbase + (unsigned)(aC0.w + f2));
    rC[4] = *(const unsigned short*)(tbase + (unsigned)(aC1.x + f2));
    rC[5] = *(const unsigned short*)(tbase + (unsigned)(aC1.y + f2));
    rC[6] = *(const unsigned short*)(tbase + (unsigned)(aC1.z + f2));
    rC[7] = *(const unsigned short*)(tbase + (unsigned)(aC1.w + f2));
    rD[0] = *(const unsigned short*)(tbase + (unsigned)(aD0.x + f2));
    rD[1] = *(const unsigned short*)(tbase + (unsigned)(aD0.y + f2));
    rD[2] = *(const unsigned short*)(tbase + (unsigned)(aD0.z + f2));
    rD[3] = *(const unsigned short*)(tbase + (unsigned)(aD0.w + f2));
    rD[4] = *(const unsigned short*)(tbase + (unsigned)(aD1.x + f2));
    rD[5] = *(const unsigned short*)(tbase + (unsigned)(aD1.y + f2));
    rD[6] = *(const unsigned short*)(tbase + (unsigned)(aD1.z + f2));
    rD[7] = *(const unsigned short*)(tbase + (unsigned)(aD1.w + f2));
    float sA01 = bf2f(rA[0]) + bf2f(rA[1]), sA23 = bf2f(rA[2]) + bf2f(rA[3]);
    float sA45 = bf2f(rA[4]) + bf2f(rA[5]), sA67 = bf2f(rA[6]) + bf2f(rA[7]);
    accA += (sA01 + sA23) + (sA45 + sA67);
    float sB01 = bf2f(rB[0]) + bf2f(rB[1]), sB23 = bf2f(rB[2]) + bf2f(rB[3]);
    float sB45 = bf2f(rB[4]) + bf2f(rB[5]), sB67 = bf2f(rB[6]) + bf2f(rB[7]);
    accB += (sB01 + sB23) + (sB45 + sB67);
    float sC01 = bf2f(rC[0]) + bf2f(rC[1]), sC23 = bf2f(rC[2]) + bf2f(rC[3]);
    float sC45 = bf2f(rC[4]) + bf2f(rC[5]), sC67 = bf2f(rC[6]) + bf2f(rC[7]);
    accC += (sC01 + sC23) + (sC45 + sC67);
    float sD01 = bf2f(rD[0]) + bf2f(rD[1]), sD23 = bf2f(rD[2]) + bf2f(rD[3]);
    float sD45 = bf2f(rD[4]) + bf2f(rD[5]), sD67 = bf2f(rD[6]) + bf2f(rD[7]);
    accD += (sD01 + sD23) + (sD45 + sD67);
}

// drain chain: x4 while all alive, then every x2 pairing, then singles.
// All bounds are wave-uniform (per-node), so branches don't diverge.
__device__ __forceinline__ void run_quad(const int* __restrict__ ep,
                                         const char* __restrict__ tbase, int f2,
                                         int jA, int eA, int jB, int eB,
                                         int jC, int eC, int jD, int eD,
                                         float& accA, float& accB, float& accC,
                                         float& accD) {
    while (jA < eA && jB < eB && jC < eC && jD < eD) {
        batch8x4(ep, jA, jB, jC, jD, tbase, f2, accA, accB, accC, accD);
        jA += 8; jB += 8; jC += 8; jD += 8;
    }
    while (jA < eA && jB < eB) { batch8x2(ep, jA, jB, tbase, f2, accA, accB); jA += 8; jB += 8; }
    while (jC < eC && jD < eD) { batch8x2(ep, jC, jD, tbase, f2, accC, accD); jC += 8; jD += 8; }
    while (jA < eA && jC < eC) { batch8x2(ep, jA, jC, tbase, f2, accA, accC); jA += 8; jC += 8; }
    while (jA < eA && jD < eD) { batch8x2(ep, jA, jD, tbase, f2, accA, accD); jA += 8; jD += 8; }
    while (jB < eB && jC < eC) { batch8x2(ep, jB, jC, tbase, f2, accB, accC); jB += 8; jC += 8; }
    while (jB < eB && jD < eD) { batch8x2(ep, jB, jD, tbase, f2, accB, accD); jB += 8; jD += 8; }
    while (jA < eA) { batch8(ep, jA, tbase, f2, accA); jA += 8; }
    while (jB < eB) { batch8(ep, jB, tbase, f2, accB); jB += 8; }
    while (jC < eC) { batch8(ep, jC, tbase, f2, accC); jC += 8; }
    while (jD < eD) { batch8(ep, jD, tbase, f2, accD); jD += 8; }
}

__global__ __launch_bounds__(256) void gather_kernel(const bf16* __restrict__ t,
                                                     const float* __restrict__ dinv,
                                                     const float* __restrict__ bias,
                                                     const int* __restrict__ rowptr,
                                                     const int* __restrict__ csw,
                                                     float* __restrict__ h,
                                                     float* __restrict__ accum_l) {
    __shared__ __attribute__((aligned(16))) int se[ECAP];  // 6.5 KB staged byte-offsets
    __shared__ int srp[GB_NODES + 1];  // staged rowptr slice
    __shared__ float s_sum[256], s_sq[256];

    int f = threadIdx.x & 63;
    int wv = threadIdx.x >> 6;
    int nb0 = blockIdx.x * GB_NODES;
    int nloc = min(GB_NODES, NN - nb0);  // 48 or 16; always multiple of 4

    for (int i = threadIdx.x; i <= nloc; i += 256) srp[i] = rowptr[nb0 + i];
    __syncthreads();
    int ebase = srp[0];
    int nE = srp[nloc] - ebase;  // multiple of 8
    bool staged = (nE <= ECAP);
    if (staged) {  // vectorized stage: ebase, nE multiples of 8 -> int4 aligned
        for (int i = threadIdx.x * 4; i < nE; i += 1024)
            *(int4*)(se + i) = *(const int4*)(csw + ebase + i);
    }
    __syncthreads();

    const char* tbase = (const char*)t - 128;  // zero-row base (pad slot 0 -> zeros)
    int f2 = f * 2;
    const unsigned short* tf = (const unsigned short*)t + f;
    float bb = bias[f];
    float sum = 0.f, sq = 0.f;

    for (int q = wv; 4 * q < nloc; q += 4) {  // wave handles node quad 4q..4q+3
        int d0 = 4 * q;
        int nA = nb0 + d0, nB = nA + 1, nC = nA + 2, nD = nA + 3;
        // init with self-loop t'[n]; dinv[n] applied at the end
        float accA = bf2f(tf[(size_t)nA * DD]);
        float accB = bf2f(tf[(size_t)nB * DD]);
        float accC = bf2f(tf[(size_t)nC * DD]);
        float accD = bf2f(tf[(size_t)nD * DD]);
        int jA = srp[d0] - ebase, eA = srp[d0 + 1] - ebase;  // multiples of 8
        int jB = eA, eB = srp[d0 + 2] - ebase;
        int jC = eB, eC = srp[d0 + 3] - ebase;
        int jD = eC, eD = srp[d0 + 4] - ebase;

        if (staged)
            run_quad(se, tbase, f2, jA, eA, jB, eB, jC, eC, jD, eD, accA, accB, accC, accD);
        else  // overflow block (vanishingly rare): csw from global
            run_quad(csw + ebase, tbase, f2, jA, eA, jB, eB, jC, eC, jD, eD,
                     accA, accB, accC, accD);

        float diA = dinv[nA], diB = dinv[nB], diC = dinv[nC], diD = dinv[nD];
        accA = accA * diA + bb;
        accB = accB * diB + bb;
        accC = accC * diC + bb;
        accD = accD * diD + bb;
        h[(size_t)nA * DD + f] = accA;
        h[(size_t)nB * DD + f] = accB;
        h[(size_t)nC * DD + f] = accC;
        h[(size_t)nD * DD + f] = accD;
        sum += accA + accB + accC + accD;
        sq += accA * accA + accB * accB + accC * accC + accD * accD;
    }
    s_sum[threadIdx.x] = sum;
    s_sq[threadIdx.x] = sq;
    __syncthreads();
    if (threadIdx.x < 64) {
        sum = s_sum[f] + s_sum[64 + f] + s_sum[128 + f] + s_sum[192 + f];
        sq = s_sq[f] + s_sq[64 + f] + s_sq[128 + f] + s_sq[192 + f];
        atomicAdd(&accum_l[f], sum);
        atomicAdd(&accum_l[64 + f], sq);
    }
}

// ---------------- pool: inline BN finalize(layer3) + ReLU + mean-pool + counts ----------------
#define POOL_CHUNK 128
__global__ __launch_bounds__(256) void pool_kernel(const float* __restrict__ hraw,
                                                   const float* __restrict__ accum_l,
                                                   const float* __restrict__ gamma,
                                                   const float* __restrict__ beta,
                                                   const int* __restrict__ batch,
                                                   float* __restrict__ pool,
                                                   float* __restrict__ counts) {
    __shared__ float ssc[64], ssh[64];
    __shared__ int s_b;
    if (threadIdx.x == 0) s_b = 0;
    if (threadIdx.x < 64) {
        float S = accum_l[threadIdx.x], Q = accum_l[64 + threadIdx.x];
        float mean = S / (float)NN;
        float var = fmaxf(Q / (float)NN - mean * mean, 0.f);
        float sc = gamma[threadIdx.x] * rsqrtf(var + BN_EPS);
        ssc[threadIdx.x] = sc;
        ssh[threadIdx.x] = beta[threadIdx.x] - mean * sc;
    }
    __syncthreads();
    // batch width detect: tail odd slots are values ~127 (int32) or high words (int64)
    if (batch[NN - 1024 + 2 * threadIdx.x + 1] != 0) atomicOr(&s_b, 1);
    __syncthreads();
    int is32 = s_b;
    int f = threadIdx.x & 63, rg = threadIdx.x >> 6;
    float sc = ssc[f], sh = ssh[f];
    int base = blockIdx.x * POOL_CHUNK;
    float acc = 0.f, cnt = 0.f;
    int cur = -1;
    for (int i = rg; i < POOL_CHUNK; i += 4) {
        int n = base + i;
        if (n >= NN) break;
        int g = ld_batch(batch, n, is32);
        if (g != cur) {
            if (cur >= 0) {
                atomicAdd(&pool[cur * DD + f], acc);
                if (f == 0) atomicAdd(&counts[cur], cnt);
            }
            acc = 0.f;
            cnt = 0.f;
            cur = g;
        }
        acc += fmaxf(hraw[(size_t)n * DD + f] * sc + sh, 0.f);
        cnt += 1.f;
    }
    if (cur >= 0) {
        atomicAdd(&pool[cur * DD + f], acc);
        if (f == 0) atomicAdd(&counts[cur], cnt);
    }
}

__global__ __launch_bounds__(256) void final_kernel(const float* __restrict__ pool,
                                                    const float* __restrict__ counts,
                                                    float* __restrict__ out) {
    int i = blockIdx.x * 256 + threadIdx.x;
    if (i < NG * DD) {
        int g = i >> 6;
        out[i] = pool[i] / fmaxf(counts[g], 1.0f);
    }
}

extern "C" void kernel_launch(void* const* d_in, const int* in_sizes, int n_in,
                              void* d_out, int out_size, void* d_ws, size_t ws_size,
                              hipStream_t stream) {
    const float* x = (const float*)d_in[0];       // [NN, DD] f32
    const int* edge_index = (const int*)d_in[1];  // [2, NE] int (width detected)
    const int* batch = (const int*)d_in[2];       // [NN] int (width detected)
    const float* Ws = (const float*)d_in[3];      // [3,64,64]
    const float* bs = (const float*)d_in[4];      // [3,64]
    const float* gammas = (const float*)d_in[5];  // [3,64]
    const float* betas = (const float*)d_in[6];   // [3,64]
    float* out = (float*)d_out;                   // [NG, DD]

    // workspace layout
    float* h = (float*)d_ws;                    // 25.6 MB (bin staging before gather 0)
    bf16* zrow = (bf16*)(h + (size_t)NN * DD);  // 128 B zero row (pad-slot target)
    bf16* t = zrow + DD;                        // 12.8 MB (t' = scaled transform)
    int* csw = (int*)(t + (size_t)NN * DD);     // CSW_CAP int (9.2 MB, padded CSR)
    float* dinv = (float*)(csw + CSW_CAP);      // 100,000 f
    int* deg_cnt = (int*)(dinv + NN);           // 100,000 i (deg, then scatter cursor)
    float* pool = (float*)(deg_cnt + NN);       // 8192 f
    float* counts = pool + NG * DD;             // 128 f
    int* bukcnt = (int*)(counts + NG);          // NBUK i
    int* ovf_cnt = bukcnt + NBUK;               // 1 i
    int* rowptr = ovf_cnt + 1;                  // 100,001 i (padded CSR offsets)
    float* accum = (float*)(rowptr + NN + 1);   // NL*128 f (BN sum/sumsq per layer)
    int* blocksum = (int*)(accum + NL * 128);   // 128 i
    unsigned short* wfrag =                     // NL*WFL shorts (48 KB), 16B-aligned
        (unsigned short*)(((uintptr_t)(blocksum + 128) + 15) & ~(uintptr_t)15);
    int2* ovf = (int2*)(wfrag + (size_t)NL * WFL);  // OVF_CAP int2 (16B-aligned)
    int* staging = (int*)h;                     // NBUK*BUK_CAP ints = 7.2 MB

    // one memset covers deg_cnt + pool + counts + bukcnt + ovf_cnt (contiguous)
    hipMemsetAsync(deg_cnt, 0, (NN + NG * DD + NG + NBUK + 1) * sizeof(int), stream);
    hipMemsetAsync(csw, 0, (size_t)CSW_CAP * sizeof(int), stream);  // pads -> zero-row
    hipMemsetAsync(zrow, 0, DD * sizeof(bf16), stream);

    bin_kernel<<<NBB, 256, 0, stream>>>(edge_index, deg_cnt, bukcnt, staging,
                                        ovf_cnt, ovf);
    scan_part_kernel<<<SCAN_BLK, 256, 0, stream>>>(deg_cnt, bukcnt, staging, blocksum,
                                                   dinv);
    scan_write_kernel<<<SCAN_BLK + NL, 256, 0, stream>>>(deg_cnt, blocksum, rowptr,
                                                         Ws, wfrag);
    scatter_kernel<<<NBUK + 1, 256, 0, stream>>>(bukcnt, staging, ovf_cnt, ovf, rowptr,
                                                 deg_cnt, csw);

    for (int l = 0; l < NL; ++l) {
        const float* hin = (l == 0) ? x : h;
        float alpha = (l == 0) ? 1.0f : 0.0f;  // identity vs ReLU on input transform
        gemm_kernel<<<NT, 256, 0, stream>>>(hin, wfrag + (size_t)l * WFL, dinv,
                                            accum + (l - 1 >= 0 ? l - 1 : 0) * 128,
                                            gammas + (size_t)(l - 1 >= 0 ? l - 1 : 0) * DD,
                                            betas + (size_t)(l - 1 >= 0 ? l - 1 : 0) * DD,
                                            (l > 0) ? 1 : 0, alpha, t, accum + l * 128);
        gather_kernel<<<GB_BLOCKS, 256, 0, stream>>>(t, dinv, bs + l * DD, rowptr, csw, h,
                                                     accum + l * 128);
    }

    pool_kernel<<<(NN + POOL_CHUNK - 1) / POOL_CHUNK, 256, 0, stream>>>(
        h, accum + 2 * 128, gammas + 2 * DD, betas + 2 * DD, batch, pool, counts);
    final_kernel<<<(NG * DD + 255) / 256, 256, 0, stream>>>(pool, counts, out);
}